// Round 1
// baseline (617.931 us; speedup 1.0000x reference)
//
#include <hip/hip_runtime.h>

#define NN 16512      // N = K + EXER nodes
#define KK 128        // feature dim
#define EE 262144     // edges per graph
#define BB 2048       // batch
#define HH 64         // history length
#define NKf ((size_t)NN * KK)

typedef unsigned int u32;

__device__ __forceinline__ float sgm(float x) { return 1.0f / (1.0f + __expf(-x)); }

// ---------------- graph preprocessing ----------------

__global__ void k_degrees(const int* __restrict__ src, const int* __restrict__ dst,
                          u32* __restrict__ dout, u32* __restrict__ din) {
  int e = blockIdx.x * 256 + threadIdx.x;
  if (e < EE) {
    atomicAdd(&dout[src[e]], 1u);
    atomicAdd(&din[dst[e]], 1u);
  }
}

// exclusive scan of in-degrees -> row_ptr, one block per graph
__global__ void k_exscan(const u32* __restrict__ cnts, u32* __restrict__ rps) {
  const u32* cnt = cnts + (size_t)blockIdx.x * NN;
  u32* rp = rps + (size_t)blockIdx.x * (NN + 1);
  __shared__ u32 buf[1024];
  __shared__ u32 carry_s;
  if (threadIdx.x == 0) carry_s = 0;
  __syncthreads();
  for (int base = 0; base < NN; base += 1024) {
    int i = base + threadIdx.x;
    u32 v = (i < NN) ? cnt[i] : 0u;
    buf[threadIdx.x] = v;
    __syncthreads();
    u32 c = carry_s;
    for (int off = 1; off < 1024; off <<= 1) {
      u32 t = (threadIdx.x >= off) ? buf[threadIdx.x - off] : 0u;
      __syncthreads();
      buf[threadIdx.x] += t;
      __syncthreads();
    }
    if (i < NN) rp[i] = c + buf[threadIdx.x] - v;   // exclusive
    __syncthreads();
    if (threadIdx.x == 1023) carry_s = c + buf[1023];
    __syncthreads();
  }
  if (threadIdx.x == 0) rp[NN] = carry_s;
}

__global__ void k_scatter(const int* __restrict__ src, const int* __restrict__ dst,
                          const u32* __restrict__ dout, const u32* __restrict__ din,
                          const u32* __restrict__ rp, u32* __restrict__ cur,
                          u32* __restrict__ csrc, float* __restrict__ cnorm) {
  int e = blockIdx.x * 256 + threadIdx.x;
  if (e >= EE) return;
  int s = src[e], d = dst[e];
  u32 pos = atomicAdd(&cur[d], 1u);
  u32 idx = rp[d] + pos;
  csrc[idx] = (u32)s;
  cnorm[idx] = rsqrtf((float)dout[s] * (float)din[d]);   // counts are >=1 for appearing nodes
}

// ---------------- SpMM: out[n,:] = sum_{e in row n} norm[e] * x[src[e],:] ----------------
// one wave per node, lane holds 2 columns (float2)

__global__ void k_spmm(const float* __restrict__ x, const u32* __restrict__ rp,
                       const u32* __restrict__ csrc, const float* __restrict__ cnorm,
                       float* __restrict__ out) {
  int w = (blockIdx.x * 256 + threadIdx.x) >> 6;
  int lane = threadIdx.x & 63;
  if (w >= NN) return;
  u32 beg = rp[w], end = rp[w + 1];
  float2 acc = make_float2(0.f, 0.f);
  u32 e = beg;
  for (; e + 2 <= end; e += 2) {
    u32 s0 = csrc[e], s1 = csrc[e + 1];
    float n0 = cnorm[e], n1 = cnorm[e + 1];
    float2 v0 = *(const float2*)(x + (size_t)s0 * KK + lane * 2);
    float2 v1 = *(const float2*)(x + (size_t)s1 * KK + lane * 2);
    acc.x += v0.x * n0; acc.y += v0.y * n0;
    acc.x += v1.x * n1; acc.y += v1.y * n1;
  }
  if (e < end) {
    u32 s0 = csrc[e]; float n0 = cnorm[e];
    float2 v0 = *(const float2*)(x + (size_t)s0 * KK + lane * 2);
    acc.x += v0.x * n0; acc.y += v0.y * n0;
  }
  *(float2*)(out + (size_t)w * KK + lane * 2) = acc;
}

// ---------------- fused 3-graph GEMM + bias + running-sum epilogue ----------------
// h_out = sum_g agg[g] @ W[g] + sum_g b[g]
// mode: 1 = Sx  = entity + v;   else Sx += v
//       2 = Ss  = v;  4 = Ss += v;   8 = skip h_out write

__global__ __launch_bounds__(256) void k_gemm3(
    const float* __restrict__ agg3, const float* __restrict__ Wg, const float* __restrict__ bg,
    float* __restrict__ hout, const float* __restrict__ entity,
    float* __restrict__ Sx, float* __restrict__ Ss, int mode)
{
  __shared__ float Wl[KK * KK];      // 64 KB
  __shared__ float Al[64 * 132];     // 33 KB, padded stride 132
  const int tid = threadIdx.x;
  const int tx = tid & 7;            // col block: cols tx*16 .. +15
  const int ty = tid >> 3;           // rows ty*2, ty*2+1
  const int rowBase = blockIdx.x * 64;

  float4 acc4[2][4];
  #pragma unroll
  for (int r = 0; r < 2; ++r)
    #pragma unroll
    for (int q = 0; q < 4; ++q) acc4[r][q] = make_float4(0.f, 0.f, 0.f, 0.f);

  for (int g = 0; g < 3; ++g) {
    const float4* __restrict__ Wg4 = (const float4*)(Wg + (size_t)g * KK * KK);
    float4* Wl4 = (float4*)Wl;
    #pragma unroll
    for (int i = 0; i < 16; ++i) Wl4[i * 256 + tid] = Wg4[i * 256 + tid];

    const float* __restrict__ Ag = agg3 + (size_t)g * NKf + (size_t)rowBase * KK;
    #pragma unroll
    for (int i = 0; i < 8; ++i) {
      int linear = i * 256 + tid;      // float4 units, 0..2047
      int r = linear >> 5;
      int c4 = linear & 31;
      ((float4*)(Al + r * 132))[c4] = ((const float4*)(Ag + (size_t)r * KK))[c4];
    }
    __syncthreads();

    #pragma unroll 2
    for (int k = 0; k < KK; ++k) {
      const float4* wrow = (const float4*)(Wl + k * KK) + tx * 4;
      float a0 = Al[(ty * 2 + 0) * 132 + k];
      float a1 = Al[(ty * 2 + 1) * 132 + k];
      #pragma unroll
      for (int q = 0; q < 4; ++q) {
        float4 wv = wrow[q];
        acc4[0][q].x += a0 * wv.x; acc4[0][q].y += a0 * wv.y;
        acc4[0][q].z += a0 * wv.z; acc4[0][q].w += a0 * wv.w;
        acc4[1][q].x += a1 * wv.x; acc4[1][q].y += a1 * wv.y;
        acc4[1][q].z += a1 * wv.z; acc4[1][q].w += a1 * wv.w;
      }
    }
    __syncthreads();
  }

  const int col = tx * 16;
  float4 bs[4];
  #pragma unroll
  for (int q = 0; q < 4; ++q) {
    int c = col + q * 4;
    float4 b0 = *(const float4*)(bg + c);
    float4 b1 = *(const float4*)(bg + KK + c);
    float4 b2 = *(const float4*)(bg + 2 * KK + c);
    bs[q] = make_float4(b0.x + b1.x + b2.x, b0.y + b1.y + b2.y,
                        b0.z + b1.z + b2.z, b0.w + b1.w + b2.w);
  }

  #pragma unroll
  for (int r = 0; r < 2; ++r) {
    int row = rowBase + ty * 2 + r;
    size_t base = (size_t)row * KK + col;
    #pragma unroll
    for (int q = 0; q < 4; ++q) {
      float4 v = make_float4(acc4[r][q].x + bs[q].x, acc4[r][q].y + bs[q].y,
                             acc4[r][q].z + bs[q].z, acc4[r][q].w + bs[q].w);
      if (!(mode & 8)) *(float4*)(hout + base + q * 4) = v;
      float4 sx;
      if (mode & 1) {
        float4 e = *(const float4*)(entity + base + q * 4);
        sx = make_float4(e.x + v.x, e.y + v.y, e.z + v.z, e.w + v.w);
      } else {
        float4 s = *(const float4*)(Sx + base + q * 4);
        sx = make_float4(s.x + v.x, s.y + v.y, s.z + v.z, s.w + v.w);
      }
      *(float4*)(Sx + base + q * 4) = sx;
      if (mode & 2) {
        *(float4*)(Ss + base + q * 4) = v;
      } else if (mode & 4) {
        float4 s = *(const float4*)(Ss + base + q * 4);
        *(float4*)(Ss + base + q * 4) = make_float4(s.x + v.x, s.y + v.y, s.z + v.z, s.w + v.w);
      }
    }
  }
}

// ---------------- downstream ----------------

__global__ void k_stuemb(const float* __restrict__ Ss, const int* __restrict__ hist,
                         const int* __restrict__ hlen, float* __restrict__ semb) {
  int w = (blockIdx.x * 256 + threadIdx.x) >> 6;
  int lane = threadIdx.x & 63;
  if (w >= BB) return;
  int len = hlen[w];
  float2 acc = make_float2(0.f, 0.f);
  for (int h = 0; h < len; ++h) {
    int id = hist[w * HH + h];
    float2 v = *(const float2*)(Ss + ((size_t)(KK + id)) * KK + lane * 2);
    acc.x += v.x; acc.y += v.y;
  }
  float sc = 0.5f / (float)len;   // stu_entity = 0.5 * Ss, then / len
  *(float2*)(semb + (size_t)w * KK + lane * 2) = make_float2(acc.x * sc, acc.y * sc);
}

__global__ void k_cproj(const float* __restrict__ Sx, const float* __restrict__ Wstu,
                        const float* __restrict__ Wexer, float* __restrict__ cstu,
                        float* __restrict__ cexer) {
  int w = (blockIdx.x * 256 + threadIdx.x) >> 6;   // concept row j
  int lane = threadIdx.x & 63;
  if (w >= KK) return;
  float2 c = *(const float2*)(Sx + (size_t)w * KK + lane * 2);
  c.x *= 0.25f; c.y *= 0.25f;
  float2 ws = *(const float2*)(Wstu + KK + lane * 2);
  float2 we = *(const float2*)(Wexer + KK + lane * 2);
  float ps = c.x * ws.x + c.y * ws.y;
  float pe = c.x * we.x + c.y * we.y;
  #pragma unroll
  for (int off = 32; off; off >>= 1) { ps += __shfl_xor(ps, off); pe += __shfl_xor(pe, off); }
  if (lane == 0) { cstu[w] = ps; cexer[w] = pe; }
}

__global__ void k_final(const float* __restrict__ Sx, const float* __restrict__ semb,
                        const float* __restrict__ cstu, const float* __restrict__ cexer,
                        const float* __restrict__ Wstu, const float* __restrict__ Wexer,
                        const float* __restrict__ W3, const float* __restrict__ disc,
                        const int* __restrict__ exid, const float* __restrict__ kn,
                        const float* __restrict__ bstu, const float* __restrict__ bexer,
                        const float* __restrict__ b3, float* __restrict__ out) {
  int w = (blockIdx.x * 256 + threadIdx.x) >> 6;   // batch index
  int lane = threadIdx.x & 63;
  if (w >= BB) return;
  int eid = exid[w];
  float2 se = *(const float2*)(Sx + ((size_t)(KK + eid)) * KK + lane * 2);
  se.x *= 0.25f; se.y *= 0.25f;                    // exer_emb
  float2 sm = *(const float2*)(semb + (size_t)w * KK + lane * 2);
  float2 ws = *(const float2*)(Wstu + lane * 2);   // Wstu[:K]
  float2 we = *(const float2*)(Wexer + lane * 2);  // Wexer[:K]
  float ps = sm.x * ws.x + sm.y * ws.y;
  float pe = se.x * we.x + se.y * we.y;
  #pragma unroll
  for (int off = 32; off; off >>= 1) { ps += __shfl_xor(ps, off); pe += __shfl_xor(pe, off); }
  float s_stu = ps + bstu[0];
  float s_exer = pe + bexer[0];
  float ed = 10.f * sgm(disc[eid]);
  float2 cs = *(const float2*)(cstu + lane * 2);
  float2 ce = *(const float2*)(cexer + lane * 2);
  float2 knv = *(const float2*)(kn + (size_t)w * KK + lane * 2);
  float x0 = ed * (sgm(s_stu + cs.x) - sgm(s_exer + ce.x)) * knv.x;
  float x1 = ed * (sgm(s_stu + cs.y) - sgm(s_exer + ce.y)) * knv.y;
  float2 w3v = *(const float2*)(W3 + lane * 2);
  float px = x0 * w3v.x + x1 * w3v.y;
  #pragma unroll
  for (int off = 32; off; off >>= 1) px += __shfl_xor(px, off);
  if (lane == 0) out[w] = sgm(px + b3[0]);
}

// ---------------- host ----------------

extern "C" void kernel_launch(void* const* d_in, const int* in_sizes, int n_in,
                              void* d_out, int out_size, void* d_ws, size_t ws_size,
                              hipStream_t stream)
{
  const float* entity = (const float*)d_in[0];
  const float* gcnW   = (const float*)d_in[1];
  const float* gcnB   = (const float*)d_in[2];
  const float* disc   = (const float*)d_in[3];
  const float* Wstu   = (const float*)d_in[4];
  const float* bstu   = (const float*)d_in[5];
  const float* Wexer  = (const float*)d_in[6];
  const float* bexer  = (const float*)d_in[7];
  const float* W3     = (const float*)d_in[8];
  const float* b3     = (const float*)d_in[9];
  const float* kn     = (const float*)d_in[10];
  const int* exer_id  = (const int*)d_in[12];
  const int* history  = (const int*)d_in[14];
  const int* hlen     = (const int*)d_in[15];
  const int* srcs[3]  = {(const int*)d_in[16], (const int*)d_in[18], (const int*)d_in[20]};
  const int* dsts[3]  = {(const int*)d_in[17], (const int*)d_in[19], (const int*)d_in[21]};

  char* ws = (char*)d_ws;
  size_t off = 0;
  auto take = [&](size_t bytes) -> char* {
    char* p = ws + off;
    off = (off + bytes + 255) & ~(size_t)255;
    return p;
  };
  float* hA    = (float*)take(NKf * 4);
  float* hB    = (float*)take(NKf * 4);
  float* Sx    = (float*)take(NKf * 4);
  float* Ss    = (float*)take(NKf * 4);
  float* agg3  = (float*)take(3 * NKf * 4);
  float* semb  = (float*)take((size_t)BB * KK * 4);
  float* cstu  = (float*)take(KK * 4);
  float* cexer = (float*)take(KK * 4);
  u32*   zbase = (u32*)take((size_t)9 * NN * 4);        // deg_out[3] | deg_in[3] | cursor[3]
  u32*   rp    = (u32*)take((size_t)3 * (NN + 1) * 4);
  u32*   csrc  = (u32*)take((size_t)3 * EE * 4);
  float* cnorm = (float*)take((size_t)3 * EE * 4);
  (void)ws_size; (void)in_sizes; (void)n_in; (void)out_size;

  hipMemsetAsync(zbase, 0, (size_t)9 * NN * 4, stream);

  for (int g = 0; g < 3; ++g)
    k_degrees<<<EE / 256, 256, 0, stream>>>(srcs[g], dsts[g], zbase + (size_t)g * NN,
                                            zbase + (size_t)(3 + g) * NN);
  k_exscan<<<3, 1024, 0, stream>>>(zbase + (size_t)3 * NN, rp);
  for (int g = 0; g < 3; ++g)
    k_scatter<<<EE / 256, 256, 0, stream>>>(srcs[g], dsts[g], zbase + (size_t)g * NN,
                                            zbase + (size_t)(3 + g) * NN, rp + (size_t)g * (NN + 1),
                                            zbase + (size_t)(6 + g) * NN, csrc + (size_t)g * EE,
                                            cnorm + (size_t)g * EE);

  const float* xs[3] = {entity, hA, hB};
  float* outs[3]     = {hA, hB, hA};
  const int modes[3] = {1, 2, 4 | 8};
  for (int l = 0; l < 3; ++l) {
    for (int g = 0; g < 3; ++g)
      k_spmm<<<NN * 64 / 256, 256, 0, stream>>>(xs[l], rp + (size_t)g * (NN + 1),
                                                csrc + (size_t)g * EE, cnorm + (size_t)g * EE,
                                                agg3 + (size_t)g * NKf);
    k_gemm3<<<NN / 64, 256, 0, stream>>>(agg3, gcnW + (size_t)l * 3 * KK * KK,
                                         gcnB + (size_t)l * 3 * KK, outs[l], entity, Sx, Ss,
                                         modes[l]);
  }

  k_stuemb<<<BB * 64 / 256, 256, 0, stream>>>(Ss, history, hlen, semb);
  k_cproj<<<KK * 64 / 256, 256, 0, stream>>>(Sx, Wstu, Wexer, cstu, cexer);
  k_final<<<BB * 64 / 256, 256, 0, stream>>>(Sx, semb, cstu, cexer, Wstu, Wexer, W3, disc,
                                             exer_id, kn, bstu, bexer, b3, (float*)d_out);
}

// Round 2
// 378.424 us; speedup vs baseline: 1.6329x; 1.6329x over previous
//
#include <hip/hip_runtime.h>

#define NN 16512      // N = K + EXER nodes
#define KK 128        // feature dim
#define K3 384        // 3 graphs concatenated along K
#define EE 262144     // edges per graph
#define BB 2048       // batch
#define HH 64         // history length
#define NKf ((size_t)NN * KK)

typedef unsigned int u32;
typedef unsigned short u16;
typedef short bf16x8 __attribute__((ext_vector_type(8)));
typedef float f32x4 __attribute__((ext_vector_type(4)));

__device__ __forceinline__ float sgm(float x) { return 1.0f / (1.0f + __expf(-x)); }

__device__ __forceinline__ u16 f2bf(float f) {          // round-to-nearest-even
  u32 u = __float_as_uint(f);
  u32 r = u + 0x7fffu + ((u >> 16) & 1u);
  return (u16)(r >> 16);
}
__device__ __forceinline__ float bflo(u32 p) { return __uint_as_float(p << 16); }
__device__ __forceinline__ float bfhi(u32 p) { return __uint_as_float(p & 0xffff0000u); }

// ---------------- graph preprocessing ----------------

__global__ void k_degrees(const int* __restrict__ s0, const int* __restrict__ d0,
                          const int* __restrict__ s1, const int* __restrict__ d1,
                          const int* __restrict__ s2, const int* __restrict__ d2,
                          u32* __restrict__ zbase) {
  int g = blockIdx.y;
  const int* src = g == 0 ? s0 : (g == 1 ? s1 : s2);
  const int* dst = g == 0 ? d0 : (g == 1 ? d1 : d2);
  u32* dout = zbase + (size_t)g * NN;
  u32* din  = zbase + (size_t)(3 + g) * NN;
  int e = blockIdx.x * 256 + threadIdx.x;     // EE == 1024*256 exactly
  atomicAdd(&dout[src[e]], 1u);
  atomicAdd(&din[dst[e]], 1u);
}

// exclusive scan of in-degrees -> row_ptr, one block per graph
__global__ void k_exscan(const u32* __restrict__ cnts, u32* __restrict__ rps) {
  const u32* cnt = cnts + (size_t)blockIdx.x * NN;
  u32* rp = rps + (size_t)blockIdx.x * (NN + 1);
  __shared__ u32 buf[1024];
  __shared__ u32 carry_s;
  if (threadIdx.x == 0) carry_s = 0;
  __syncthreads();
  for (int base = 0; base < NN; base += 1024) {
    int i = base + threadIdx.x;
    u32 v = (i < NN) ? cnt[i] : 0u;
    buf[threadIdx.x] = v;
    __syncthreads();
    u32 c = carry_s;
    for (int off = 1; off < 1024; off <<= 1) {
      u32 t = (threadIdx.x >= off) ? buf[threadIdx.x - off] : 0u;
      __syncthreads();
      buf[threadIdx.x] += t;
      __syncthreads();
    }
    if (i < NN) rp[i] = c + buf[threadIdx.x] - v;   // exclusive
    __syncthreads();
    if (threadIdx.x == 1023) carry_s = c + buf[1023];
    __syncthreads();
  }
  if (threadIdx.x == 0) rp[NN] = carry_s;
}

__global__ void k_scatter(const int* __restrict__ s0, const int* __restrict__ d0,
                          const int* __restrict__ s1, const int* __restrict__ d1,
                          const int* __restrict__ s2, const int* __restrict__ d2,
                          u32* __restrict__ zbase, const u32* __restrict__ rps,
                          u32* __restrict__ csrcs, float* __restrict__ cnorms) {
  int g = blockIdx.y;
  const int* src = g == 0 ? s0 : (g == 1 ? s1 : s2);
  const int* dst = g == 0 ? d0 : (g == 1 ? d1 : d2);
  const u32* dout = zbase + (size_t)g * NN;
  const u32* din  = zbase + (size_t)(3 + g) * NN;
  u32* cur = zbase + (size_t)(6 + g) * NN;
  const u32* rp = rps + (size_t)g * (NN + 1);
  u32* csrc = csrcs + (size_t)g * EE;
  float* cnorm = cnorms + (size_t)g * EE;
  int e = blockIdx.x * 256 + threadIdx.x;
  int s = src[e], d = dst[e];
  u32 pos = atomicAdd(&cur[d], 1u);
  u32 idx = rp[d] + pos;
  csrc[idx] = (u32)s;
  cnorm[idx] = rsqrtf((float)dout[s] * (float)din[d]);
}

// ---------------- weight pre-swizzle into MFMA B-fragment order ----------------
// Bsw[((l*96 + nb*12 + ks)*64 + lane)*8 + j] = bf16( W[l, g, kin, kout] )
//   k = ks*32 + (lane>>4)*8 + j ; g = k>>7 ; kin = k&127 ; kout = nb*16 + (lane&15)

__global__ void k_prepB(const float* __restrict__ W, u16* __restrict__ Bsw) {
  int t = blockIdx.x * 256 + threadIdx.x;   // 0 .. 18431
  if (t >= 3 * 8 * 12 * 64) return;
  int lane = t & 63;
  int ks = (t >> 6) % 12;
  int nb = ((t >> 6) / 12) % 8;
  int l  = (t >> 6) / 96;
  int kout = nb * 16 + (lane & 15);
  int kb = ks * 32 + (lane >> 4) * 8;
  bf16x8 v;
  #pragma unroll
  for (int j = 0; j < 8; ++j) {
    int k = kb + j; int g = k >> 7; int kin = k & 127;
    v[j] = (short)f2bf(W[(((size_t)l * 3 + g) * KK + kin) * KK + kout]);
  }
  *(bf16x8*)(Bsw + (size_t)t * 8) = v;
}

__global__ void k_prepbias(const float* __restrict__ b, float* __restrict__ bsum) {
  int l = blockIdx.x, c = threadIdx.x;
  bsum[l * KK + c] = b[(l * 3 + 0) * KK + c] + b[(l * 3 + 1) * KK + c] + b[(l * 3 + 2) * KK + c];
}

__global__ void k_cvt(const float* __restrict__ in, u16* __restrict__ out) {
  int t = blockIdx.x * 256 + threadIdx.x;   // NN*KK/8 = 264192 threads
  if (t >= NN * KK / 8) return;
  const float4* p = (const float4*)in + (size_t)t * 2;
  float4 v0 = p[0], v1 = p[1];
  bf16x8 o;
  o[0] = (short)f2bf(v0.x); o[1] = (short)f2bf(v0.y);
  o[2] = (short)f2bf(v0.z); o[3] = (short)f2bf(v0.w);
  o[4] = (short)f2bf(v1.x); o[5] = (short)f2bf(v1.y);
  o[6] = (short)f2bf(v1.z); o[7] = (short)f2bf(v1.w);
  *(bf16x8*)(out + (size_t)t * 8) = o;
}

// ---------------- SpMM (bf16 x, fp32 accumulate, bf16 interleaved agg out) ----------------

__global__ void k_spmm(const u16* __restrict__ x, const u32* __restrict__ rps,
                       const u32* __restrict__ csrcs, const float* __restrict__ cnorms,
                       u16* __restrict__ agg) {
  int g = blockIdx.y;
  const u32* rp = rps + (size_t)g * (NN + 1);
  const u32* csrc = csrcs + (size_t)g * EE;
  const float* cnorm = cnorms + (size_t)g * EE;
  int w = (blockIdx.x * 256 + threadIdx.x) >> 6;
  int lane = threadIdx.x & 63;
  if (w >= NN) return;
  u32 beg = rp[w], end = rp[w + 1];
  float a0 = 0.f, a1 = 0.f;
  u32 e = beg;
  for (; e + 2 <= end; e += 2) {
    u32 s0 = csrc[e], s1 = csrc[e + 1];
    float n0 = cnorm[e], n1 = cnorm[e + 1];
    u32 p0 = *(const u32*)(x + (size_t)s0 * KK + lane * 2);
    u32 p1 = *(const u32*)(x + (size_t)s1 * KK + lane * 2);
    a0 += bflo(p0) * n0 + bflo(p1) * n1;
    a1 += bfhi(p0) * n0 + bfhi(p1) * n1;
  }
  if (e < end) {
    u32 s0 = csrc[e]; float n0 = cnorm[e];
    u32 p0 = *(const u32*)(x + (size_t)s0 * KK + lane * 2);
    a0 += bflo(p0) * n0;
    a1 += bfhi(p0) * n0;
  }
  u32 pk = ((u32)f2bf(a1) << 16) | (u32)f2bf(a0);
  *(u32*)(agg + (size_t)w * K3 + g * KK + lane * 2) = pk;
}

// ---------------- MFMA GEMM: h = agg[M,384] @ B[384,128] + bsum, fused epilogue ----------
// mode: 1 = Sx = entity + v ; else Sx += v
//       2 = Ss = v ; 4 = Ss += v ; 8 = skip h write

__global__ __launch_bounds__(256) void k_gemm(
    const u16* __restrict__ agg, const u16* __restrict__ Bsw, const float* __restrict__ bsum,
    u16* __restrict__ hout, const float* __restrict__ entity,
    float* __restrict__ Sx, float* __restrict__ Ss, int mode)
{
  const int tid = threadIdx.x;
  const int wv = tid >> 6, lane = tid & 63;
  const int m0 = blockIdx.x * 32;
  const int n0 = wv * 32;
  const int lr = lane & 15;        // A row-in-frag / B,C col
  const int lk = lane >> 4;        // k-group of 8

  f32x4 z = {0.f, 0.f, 0.f, 0.f};
  f32x4 acc[2][2] = {{z, z}, {z, z}};

  const u16* aA = agg + (size_t)(m0 + lr) * K3 + lk * 8;          // +i*16*384, +ks*32
  const u16* aB = Bsw + (size_t)(wv * 2) * 6144 + (size_t)lane * 8; // +j*6144, +ks*512

  #pragma unroll
  for (int ks = 0; ks < 12; ++ks) {
    bf16x8 a0 = *(const bf16x8*)(aA + ks * 32);
    bf16x8 a1 = *(const bf16x8*)(aA + 16 * K3 + ks * 32);
    bf16x8 b0 = *(const bf16x8*)(aB + ks * 512);
    bf16x8 b1 = *(const bf16x8*)(aB + 6144 + ks * 512);
    acc[0][0] = __builtin_amdgcn_mfma_f32_16x16x32_bf16(a0, b0, acc[0][0], 0, 0, 0);
    acc[0][1] = __builtin_amdgcn_mfma_f32_16x16x32_bf16(a0, b1, acc[0][1], 0, 0, 0);
    acc[1][0] = __builtin_amdgcn_mfma_f32_16x16x32_bf16(a1, b0, acc[1][0], 0, 0, 0);
    acc[1][1] = __builtin_amdgcn_mfma_f32_16x16x32_bf16(a1, b1, acc[1][1], 0, 0, 0);
  }

  #pragma unroll
  for (int j = 0; j < 2; ++j) {
    int col = n0 + j * 16 + lr;
    float bv = bsum[col];
    #pragma unroll
    for (int i = 0; i < 2; ++i) {
      int rowb = m0 + i * 16 + lk * 4;
      #pragma unroll
      for (int r = 0; r < 4; ++r) {
        size_t idx = (size_t)(rowb + r) * KK + col;
        float v = acc[i][j][r] + bv;
        if (!(mode & 8)) hout[idx] = f2bf(v);
        float sx = (mode & 1) ? (entity[idx] + v) : (Sx[idx] + v);
        Sx[idx] = sx;
        if (mode & 2) Ss[idx] = v;
        else if (mode & 4) Ss[idx] += v;
      }
    }
  }
}

// ---------------- downstream ----------------

__global__ void k_stuemb(const float* __restrict__ Ss, const int* __restrict__ hist,
                         const int* __restrict__ hlen, float* __restrict__ semb) {
  int w = (blockIdx.x * 256 + threadIdx.x) >> 6;
  int lane = threadIdx.x & 63;
  if (w >= BB) return;
  int len = hlen[w];
  float2 acc = make_float2(0.f, 0.f);
  for (int h = 0; h < len; ++h) {
    int id = hist[w * HH + h];
    float2 v = *(const float2*)(Ss + ((size_t)(KK + id)) * KK + lane * 2);
    acc.x += v.x; acc.y += v.y;
  }
  float sc = 0.5f / (float)len;   // stu_entity = 0.5 * Ss, then / len
  *(float2*)(semb + (size_t)w * KK + lane * 2) = make_float2(acc.x * sc, acc.y * sc);
}

__global__ void k_cproj(const float* __restrict__ Sx, const float* __restrict__ Wstu,
                        const float* __restrict__ Wexer, float* __restrict__ cstu,
                        float* __restrict__ cexer) {
  int w = (blockIdx.x * 256 + threadIdx.x) >> 6;   // concept row j
  int lane = threadIdx.x & 63;
  if (w >= KK) return;
  float2 c = *(const float2*)(Sx + (size_t)w * KK + lane * 2);
  c.x *= 0.25f; c.y *= 0.25f;
  float2 ws = *(const float2*)(Wstu + KK + lane * 2);
  float2 we = *(const float2*)(Wexer + KK + lane * 2);
  float ps = c.x * ws.x + c.y * ws.y;
  float pe = c.x * we.x + c.y * we.y;
  #pragma unroll
  for (int off = 32; off; off >>= 1) { ps += __shfl_xor(ps, off); pe += __shfl_xor(pe, off); }
  if (lane == 0) { cstu[w] = ps; cexer[w] = pe; }
}

__global__ void k_final(const float* __restrict__ Sx, const float* __restrict__ semb,
                        const float* __restrict__ cstu, const float* __restrict__ cexer,
                        const float* __restrict__ Wstu, const float* __restrict__ Wexer,
                        const float* __restrict__ W3, const float* __restrict__ disc,
                        const int* __restrict__ exid, const float* __restrict__ kn,
                        const float* __restrict__ bstu, const float* __restrict__ bexer,
                        const float* __restrict__ b3, float* __restrict__ out) {
  int w = (blockIdx.x * 256 + threadIdx.x) >> 6;   // batch index
  int lane = threadIdx.x & 63;
  if (w >= BB) return;
  int eid = exid[w];
  float2 se = *(const float2*)(Sx + ((size_t)(KK + eid)) * KK + lane * 2);
  se.x *= 0.25f; se.y *= 0.25f;                    // exer_emb
  float2 sm = *(const float2*)(semb + (size_t)w * KK + lane * 2);
  float2 ws = *(const float2*)(Wstu + lane * 2);
  float2 we = *(const float2*)(Wexer + lane * 2);
  float ps = sm.x * ws.x + sm.y * ws.y;
  float pe = se.x * we.x + se.y * we.y;
  #pragma unroll
  for (int off = 32; off; off >>= 1) { ps += __shfl_xor(ps, off); pe += __shfl_xor(pe, off); }
  float s_stu = ps + bstu[0];
  float s_exer = pe + bexer[0];
  float ed = 10.f * sgm(disc[eid]);
  float2 cs = *(const float2*)(cstu + lane * 2);
  float2 ce = *(const float2*)(cexer + lane * 2);
  float2 knv = *(const float2*)(kn + (size_t)w * KK + lane * 2);
  float x0 = ed * (sgm(s_stu + cs.x) - sgm(s_exer + ce.x)) * knv.x;
  float x1 = ed * (sgm(s_stu + cs.y) - sgm(s_exer + ce.y)) * knv.y;
  float2 w3v = *(const float2*)(W3 + lane * 2);
  float px = x0 * w3v.x + x1 * w3v.y;
  #pragma unroll
  for (int off = 32; off; off >>= 1) px += __shfl_xor(px, off);
  if (lane == 0) out[w] = sgm(px + b3[0]);
}

// ---------------- host ----------------

extern "C" void kernel_launch(void* const* d_in, const int* in_sizes, int n_in,
                              void* d_out, int out_size, void* d_ws, size_t ws_size,
                              hipStream_t stream)
{
  const float* entity = (const float*)d_in[0];
  const float* gcnW   = (const float*)d_in[1];
  const float* gcnB   = (const float*)d_in[2];
  const float* disc   = (const float*)d_in[3];
  const float* Wstu   = (const float*)d_in[4];
  const float* bstu   = (const float*)d_in[5];
  const float* Wexer  = (const float*)d_in[6];
  const float* bexer  = (const float*)d_in[7];
  const float* W3     = (const float*)d_in[8];
  const float* b3     = (const float*)d_in[9];
  const float* kn     = (const float*)d_in[10];
  const int* exer_id  = (const int*)d_in[12];
  const int* history  = (const int*)d_in[14];
  const int* hlen     = (const int*)d_in[15];
  const int* s0 = (const int*)d_in[16], *dd0 = (const int*)d_in[17];
  const int* s1 = (const int*)d_in[18], *dd1 = (const int*)d_in[19];
  const int* s2 = (const int*)d_in[20], *dd2 = (const int*)d_in[21];

  char* ws = (char*)d_ws;
  size_t off = 0;
  auto take = [&](size_t bytes) -> char* {
    char* p = ws + off;
    off = (off + bytes + 255) & ~(size_t)255;
    return p;
  };
  u16*   xent  = (u16*)take(NKf * 2);
  u16*   hA    = (u16*)take(NKf * 2);
  u16*   hB    = (u16*)take(NKf * 2);
  float* Sx    = (float*)take(NKf * 4);
  float* Ss    = (float*)take(NKf * 4);
  u16*   agg   = (u16*)take((size_t)NN * K3 * 2);
  float* semb  = (float*)take((size_t)BB * KK * 4);
  float* cstu  = (float*)take(KK * 4);
  float* cexer = (float*)take(KK * 4);
  u16*   Bsw   = (u16*)take((size_t)3 * 49152 * 2);
  float* bsum  = (float*)take((size_t)3 * KK * 4);
  u32*   zbase = (u32*)take((size_t)9 * NN * 4);   // deg_out[3] | deg_in[3] | cursor[3]
  u32*   rp    = (u32*)take((size_t)3 * (NN + 1) * 4);
  u32*   csrc  = (u32*)take((size_t)3 * EE * 4);
  float* cnorm = (float*)take((size_t)3 * EE * 4);
  (void)ws_size; (void)in_sizes; (void)n_in; (void)out_size;

  hipMemsetAsync(zbase, 0, (size_t)9 * NN * 4, stream);

  k_degrees<<<dim3(EE / 256, 3), 256, 0, stream>>>(s0, dd0, s1, dd1, s2, dd2, zbase);
  k_exscan<<<3, 1024, 0, stream>>>(zbase + (size_t)3 * NN, rp);
  k_scatter<<<dim3(EE / 256, 3), 256, 0, stream>>>(s0, dd0, s1, dd1, s2, dd2, zbase, rp, csrc, cnorm);
  k_cvt<<<(NN * KK / 8 + 255) / 256, 256, 0, stream>>>(entity, xent);
  k_prepB<<<72, 256, 0, stream>>>(gcnW, Bsw);
  k_prepbias<<<3, KK, 0, stream>>>(gcnB, bsum);

  const u16* xs[3] = {xent, hA, hB};
  u16* outs[3]     = {hA, hB, nullptr};
  const int modes[3] = {1, 2, 4 | 8};
  for (int l = 0; l < 3; ++l) {
    k_spmm<<<dim3(NN * 64 / 256, 3), 256, 0, stream>>>(xs[l], rp, csrc, cnorm, agg);
    k_gemm<<<NN / 32, 256, 0, stream>>>(agg, Bsw + (size_t)l * 49152, bsum + (size_t)l * KK,
                                        outs[l], entity, Sx, Ss, modes[l]);
  }

  k_stuemb<<<BB * 64 / 256, 256, 0, stream>>>(Ss, history, hlen, semb);
  k_cproj<<<KK * 64 / 256, 256, 0, stream>>>(Sx, Wstu, Wexer, cstu, cexer);
  k_final<<<BB * 64 / 256, 256, 0, stream>>>(Sx, semb, cstu, cexer, Wstu, Wexer, W3, disc,
                                             exer_id, kn, bstu, bexer, b3, (float*)d_out);
}

// Round 3
// 260.845 us; speedup vs baseline: 2.3690x; 1.4508x over previous
//
#include <hip/hip_runtime.h>

#define NN 16512      // N = K + EXER nodes
#define KK 128        // feature dim
#define K3 384        // 3 graphs concatenated along K
#define EE 262144     // edges per graph
#define BB 2048       // batch
#define HH 64         // history length
#define NKf ((size_t)NN * KK)
#define NB 64         // hist blocks per graph
#define EPB (EE / NB) // 4096 edges per block
#define NP (NN / 2)   // 8256 packed u16-pair counters

typedef unsigned int u32;
typedef unsigned short u16;
typedef short bf16x8 __attribute__((ext_vector_type(8)));
typedef float f32x4 __attribute__((ext_vector_type(4)));

__device__ __forceinline__ float sgm(float x) { return 1.0f / (1.0f + __expf(-x)); }

__device__ __forceinline__ u16 f2bf(float f) {          // round-to-nearest-even
  u32 u = __float_as_uint(f);
  u32 r = u + 0x7fffu + ((u >> 16) & 1u);
  return (u16)(r >> 16);
}
__device__ __forceinline__ float bflo(u32 p) { return __uint_as_float(p << 16); }
__device__ __forceinline__ float bfhi(u32 p) { return __uint_as_float(p & 0xffff0000u); }

// ---------------- graph preprocessing (atomic-free counting sort) ----------------

// per-block private LDS histograms -> global slabs (no global atomics)
__global__ __launch_bounds__(256) void k_hist(
    const int* __restrict__ s0, const int* __restrict__ d0,
    const int* __restrict__ s1, const int* __restrict__ d1,
    const int* __restrict__ s2, const int* __restrict__ d2,
    u32* __restrict__ slabO, u32* __restrict__ slabI) {
  int g = blockIdx.y, b = blockIdx.x;
  const int* src = g == 0 ? s0 : (g == 1 ? s1 : s2);
  const int* dst = g == 0 ? d0 : (g == 1 ? d1 : d2);
  __shared__ u32 hO[NP], hI[NP];
  for (int i = threadIdx.x; i < NP; i += 256) { hO[i] = 0; hI[i] = 0; }
  __syncthreads();
  int base = b * EPB;
  for (int i = threadIdx.x; i < EPB; i += 256) {
    int s = src[base + i], d = dst[base + i];
    atomicAdd(&hO[s >> 1], 1u << ((s & 1) * 16));
    atomicAdd(&hI[d >> 1], 1u << ((d & 1) * 16));
  }
  __syncthreads();
  u32* oO = slabO + ((size_t)g * NB + b) * NP;
  u32* oI = slabI + ((size_t)g * NB + b) * NP;
  for (int i = threadIdx.x; i < NP; i += 256) { oO[i] = hO[i]; oI[i] = hI[i]; }
}

// sum slabs -> degrees (+rsqrt tables); in-place turn in-slabs into per-block prefixes
__global__ void k_reduce(u32* __restrict__ slabO, u32* __restrict__ slabI,
                         u32* __restrict__ degI, float* __restrict__ rsdO,
                         float* __restrict__ rsdI) {
  int g = blockIdx.y;
  int t = blockIdx.x * 256 + threadIdx.x;
  if (t >= NP) return;
  u32* sO = slabO + (size_t)g * NB * NP + t;
  u32* sI = slabI + (size_t)g * NB * NP + t;
  u32 sumO = 0, pre = 0;
  #pragma unroll 8
  for (int b = 0; b < NB; ++b) sumO += sO[(size_t)b * NP];
  #pragma unroll 8
  for (int b = 0; b < NB; ++b) {
    u32 v = sI[(size_t)b * NP];
    sI[(size_t)b * NP] = pre;          // packed u16 exclusive prefix (no overflow: deg small)
    pre += v;
  }
  u32 dOl = sumO & 0xffffu, dOh = sumO >> 16;
  u32 dIl = pre & 0xffffu,  dIh = pre >> 16;
  *(uint2*)(degI + (size_t)g * NN + 2 * t) = make_uint2(dIl, dIh);
  *(float2*)(rsdO + (size_t)g * NN + 2 * t) =
      make_float2(rsqrtf((float)(dOl ? dOl : 1u)), rsqrtf((float)(dOh ? dOh : 1u)));
  *(float2*)(rsdI + (size_t)g * NN + 2 * t) =
      make_float2(rsqrtf((float)(dIl ? dIl : 1u)), rsqrtf((float)(dIh ? dIh : 1u)));
}

// exclusive scan of in-degrees -> row_ptr; one block per graph
__global__ __launch_bounds__(1024) void k_exscan2(const u32* __restrict__ degI,
                                                  u32* __restrict__ rps) {
  int g = blockIdx.x;
  const u32* deg = degI + (size_t)g * NN;
  u32* rp = rps + (size_t)g * (NN + 1);
  int t = threadIdx.x;
  int i0 = t * 17, i1 = i0 + 17 < NN ? i0 + 17 : NN;
  u32 s = 0;
  for (int i = i0; i < i1; ++i) s += deg[i];
  u32 x = s;
  int lane = t & 63, wid = t >> 6;
  #pragma unroll
  for (int off = 1; off < 64; off <<= 1) {
    u32 y = __shfl_up(x, off);
    if (lane >= off) x += y;
  }
  __shared__ u32 wsums[16];
  if (lane == 63) wsums[wid] = x;
  __syncthreads();
  if (t == 0) {
    u32 run = 0;
    #pragma unroll
    for (int i = 0; i < 16; ++i) { u32 tmp = wsums[i]; wsums[i] = run; run += tmp; }
  }
  __syncthreads();
  u32 run = wsums[wid] + x - s;     // exclusive prefix for this thread
  for (int i = i0; i < i1; ++i) { rp[i] = run; run += deg[i]; }
  if (t == 0) rp[NN] = EE;
}

// place edges: LDS cursor = rp + per-block prefix; LDS atomics only, plain global stores
__global__ __launch_bounds__(256) void k_scatter2(
    const int* __restrict__ s0, const int* __restrict__ d0,
    const int* __restrict__ s1, const int* __restrict__ d1,
    const int* __restrict__ s2, const int* __restrict__ d2,
    const u32* __restrict__ slabI, const u32* __restrict__ rps,
    const float* __restrict__ rsdO, const float* __restrict__ rsdI,
    u32* __restrict__ csrcs, float* __restrict__ cnorms) {
  int g = blockIdx.y, b = blockIdx.x;
  const int* src = g == 0 ? s0 : (g == 1 ? s1 : s2);
  const int* dst = g == 0 ? d0 : (g == 1 ? d1 : d2);
  const u32* rp = rps + (size_t)g * (NN + 1);
  const u32* pre = slabI + ((size_t)g * NB + b) * NP;
  const float* rO = rsdO + (size_t)g * NN;
  const float* rI = rsdI + (size_t)g * NN;
  u32* cs = csrcs + (size_t)g * EE;
  float* cn = cnorms + (size_t)g * EE;
  __shared__ u32 cur[NN];
  for (int i = threadIdx.x; i < NP; i += 256) {
    u32 p = pre[i];
    cur[2 * i]     = rp[2 * i] + (p & 0xffffu);
    cur[2 * i + 1] = rp[2 * i + 1] + (p >> 16);
  }
  __syncthreads();
  int base = b * EPB;
  for (int i = threadIdx.x; i < EPB; i += 256) {
    int s = src[base + i], d = dst[base + i];
    u32 idx = atomicAdd(&cur[d], 1u);
    cs[idx] = (u32)s;
    cn[idx] = rO[s] * rI[d];
  }
}

// ---------------- weight pre-swizzle into MFMA B-fragment order ----------------
// Bsw[((l*96 + nb*12 + ks)*64 + lane)*8 + j] = bf16( W[l, g, kin, kout] )
//   k = ks*32 + (lane>>4)*8 + j ; g = k>>7 ; kin = k&127 ; kout = nb*16 + (lane&15)

__global__ void k_prepB(const float* __restrict__ W, u16* __restrict__ Bsw) {
  int t = blockIdx.x * 256 + threadIdx.x;   // 0 .. 18431
  if (t >= 3 * 8 * 12 * 64) return;
  int lane = t & 63;
  int ks = (t >> 6) % 12;
  int nb = ((t >> 6) / 12) % 8;
  int l  = (t >> 6) / 96;
  int kout = nb * 16 + (lane & 15);
  int kb = ks * 32 + (lane >> 4) * 8;
  bf16x8 v;
  #pragma unroll
  for (int j = 0; j < 8; ++j) {
    int k = kb + j; int g = k >> 7; int kin = k & 127;
    v[j] = (short)f2bf(W[(((size_t)l * 3 + g) * KK + kin) * KK + kout]);
  }
  *(bf16x8*)(Bsw + (size_t)t * 8) = v;
}

__global__ void k_prepbias(const float* __restrict__ b, float* __restrict__ bsum) {
  int l = blockIdx.x, c = threadIdx.x;
  bsum[l * KK + c] = b[(l * 3 + 0) * KK + c] + b[(l * 3 + 1) * KK + c] + b[(l * 3 + 2) * KK + c];
}

__global__ void k_cvt(const float* __restrict__ in, u16* __restrict__ out) {
  int t = blockIdx.x * 256 + threadIdx.x;   // NN*KK/8 threads
  if (t >= NN * KK / 8) return;
  const float4* p = (const float4*)in + (size_t)t * 2;
  float4 v0 = p[0], v1 = p[1];
  bf16x8 o;
  o[0] = (short)f2bf(v0.x); o[1] = (short)f2bf(v0.y);
  o[2] = (short)f2bf(v0.z); o[3] = (short)f2bf(v0.w);
  o[4] = (short)f2bf(v1.x); o[5] = (short)f2bf(v1.y);
  o[6] = (short)f2bf(v1.z); o[7] = (short)f2bf(v1.w);
  *(bf16x8*)(out + (size_t)t * 8) = o;
}

// ---------------- SpMM (bf16 x, fp32 accumulate, bf16 interleaved agg out) ----------------

__global__ void k_spmm(const u16* __restrict__ x, const u32* __restrict__ rps,
                       const u32* __restrict__ csrcs, const float* __restrict__ cnorms,
                       u16* __restrict__ agg) {
  int g = blockIdx.y;
  const u32* rp = rps + (size_t)g * (NN + 1);
  const u32* csrc = csrcs + (size_t)g * EE;
  const float* cnorm = cnorms + (size_t)g * EE;
  int w = (blockIdx.x * 256 + threadIdx.x) >> 6;
  int lane = threadIdx.x & 63;
  if (w >= NN) return;
  w = __builtin_amdgcn_readfirstlane(w);     // wave-uniform: scalarize rp/csrc/cnorm loads
  u32 beg = rp[w], end = rp[w + 1];
  float a0 = 0.f, a1 = 0.f;
  u32 e = beg;
  for (; e + 2 <= end; e += 2) {
    u32 s0 = csrc[e], s1 = csrc[e + 1];
    float n0 = cnorm[e], n1 = cnorm[e + 1];
    u32 p0 = *(const u32*)(x + (size_t)s0 * KK + lane * 2);
    u32 p1 = *(const u32*)(x + (size_t)s1 * KK + lane * 2);
    a0 += bflo(p0) * n0 + bflo(p1) * n1;
    a1 += bfhi(p0) * n0 + bfhi(p1) * n1;
  }
  if (e < end) {
    u32 s0 = csrc[e]; float n0 = cnorm[e];
    u32 p0 = *(const u32*)(x + (size_t)s0 * KK + lane * 2);
    a0 += bflo(p0) * n0;
    a1 += bfhi(p0) * n0;
  }
  u32 pk = ((u32)f2bf(a1) << 16) | (u32)f2bf(a0);
  *(u32*)(agg + (size_t)w * K3 + g * KK + lane * 2) = pk;
}

// ---------------- MFMA GEMM: h = agg[M,384] @ B[384,128] + bsum, fused epilogue ----------
// mode: 1 = Sx = entity + v ; else Sx += v
//       2 = Ss = v ; 4 = Ss += v ; 8 = skip h write

__global__ __launch_bounds__(256) void k_gemm(
    const u16* __restrict__ agg, const u16* __restrict__ Bsw, const float* __restrict__ bsum,
    u16* __restrict__ hout, const float* __restrict__ entity,
    float* __restrict__ Sx, float* __restrict__ Ss, int mode)
{
  const int tid = threadIdx.x;
  const int wv = tid >> 6, lane = tid & 63;
  const int m0 = blockIdx.x * 32;
  const int n0 = wv * 32;
  const int lr = lane & 15;        // A row-in-frag / B,C col
  const int lk = lane >> 4;        // k-group of 8

  f32x4 z = {0.f, 0.f, 0.f, 0.f};
  f32x4 acc[2][2] = {{z, z}, {z, z}};

  const u16* aA = agg + (size_t)(m0 + lr) * K3 + lk * 8;            // +i*16*384, +ks*32
  const u16* aB = Bsw + (size_t)(wv * 2) * 6144 + (size_t)lane * 8; // +j*6144, +ks*512

  #pragma unroll
  for (int ks = 0; ks < 12; ++ks) {
    bf16x8 a0 = *(const bf16x8*)(aA + ks * 32);
    bf16x8 a1 = *(const bf16x8*)(aA + 16 * K3 + ks * 32);
    bf16x8 b0 = *(const bf16x8*)(aB + ks * 512);
    bf16x8 b1 = *(const bf16x8*)(aB + 6144 + ks * 512);
    acc[0][0] = __builtin_amdgcn_mfma_f32_16x16x32_bf16(a0, b0, acc[0][0], 0, 0, 0);
    acc[0][1] = __builtin_amdgcn_mfma_f32_16x16x32_bf16(a0, b1, acc[0][1], 0, 0, 0);
    acc[1][0] = __builtin_amdgcn_mfma_f32_16x16x32_bf16(a1, b0, acc[1][0], 0, 0, 0);
    acc[1][1] = __builtin_amdgcn_mfma_f32_16x16x32_bf16(a1, b1, acc[1][1], 0, 0, 0);
  }

  #pragma unroll
  for (int j = 0; j < 2; ++j) {
    int col = n0 + j * 16 + lr;
    float bv = bsum[col];
    #pragma unroll
    for (int i = 0; i < 2; ++i) {
      int rowb = m0 + i * 16 + lk * 4;
      #pragma unroll
      for (int r = 0; r < 4; ++r) {
        size_t idx = (size_t)(rowb + r) * KK + col;
        float v = acc[i][j][r] + bv;
        if (!(mode & 8)) hout[idx] = f2bf(v);
        float sx = (mode & 1) ? (entity[idx] + v) : (Sx[idx] + v);
        Sx[idx] = sx;
        if (mode & 2) Ss[idx] = v;
        else if (mode & 4) Ss[idx] += v;
      }
    }
  }
}

// ---------------- downstream ----------------

__global__ void k_stuemb(const float* __restrict__ Ss, const int* __restrict__ hist,
                         const int* __restrict__ hlen, float* __restrict__ semb) {
  int w = (blockIdx.x * 256 + threadIdx.x) >> 6;
  int lane = threadIdx.x & 63;
  if (w >= BB) return;
  int len = hlen[w];
  float2 acc = make_float2(0.f, 0.f);
  for (int h = 0; h < len; ++h) {
    int id = hist[w * HH + h];
    float2 v = *(const float2*)(Ss + ((size_t)(KK + id)) * KK + lane * 2);
    acc.x += v.x; acc.y += v.y;
  }
  float sc = 0.5f / (float)len;   // stu_entity = 0.5 * Ss, then / len
  *(float2*)(semb + (size_t)w * KK + lane * 2) = make_float2(acc.x * sc, acc.y * sc);
}

__global__ void k_cproj(const float* __restrict__ Sx, const float* __restrict__ Wstu,
                        const float* __restrict__ Wexer, float* __restrict__ cstu,
                        float* __restrict__ cexer) {
  int w = (blockIdx.x * 256 + threadIdx.x) >> 6;   // concept row j
  int lane = threadIdx.x & 63;
  if (w >= KK) return;
  float2 c = *(const float2*)(Sx + (size_t)w * KK + lane * 2);
  c.x *= 0.25f; c.y *= 0.25f;
  float2 ws = *(const float2*)(Wstu + KK + lane * 2);
  float2 we = *(const float2*)(Wexer + KK + lane * 2);
  float ps = c.x * ws.x + c.y * ws.y;
  float pe = c.x * we.x + c.y * we.y;
  #pragma unroll
  for (int off = 32; off; off >>= 1) { ps += __shfl_xor(ps, off); pe += __shfl_xor(pe, off); }
  if (lane == 0) { cstu[w] = ps; cexer[w] = pe; }
}

__global__ void k_final(const float* __restrict__ Sx, const float* __restrict__ semb,
                        const float* __restrict__ cstu, const float* __restrict__ cexer,
                        const float* __restrict__ Wstu, const float* __restrict__ Wexer,
                        const float* __restrict__ W3, const float* __restrict__ disc,
                        const int* __restrict__ exid, const float* __restrict__ kn,
                        const float* __restrict__ bstu, const float* __restrict__ bexer,
                        const float* __restrict__ b3, float* __restrict__ out) {
  int w = (blockIdx.x * 256 + threadIdx.x) >> 6;   // batch index
  int lane = threadIdx.x & 63;
  if (w >= BB) return;
  int eid = exid[w];
  float2 se = *(const float2*)(Sx + ((size_t)(KK + eid)) * KK + lane * 2);
  se.x *= 0.25f; se.y *= 0.25f;                    // exer_emb
  float2 sm = *(const float2*)(semb + (size_t)w * KK + lane * 2);
  float2 ws = *(const float2*)(Wstu + lane * 2);
  float2 we = *(const float2*)(Wexer + lane * 2);
  float ps = sm.x * ws.x + sm.y * ws.y;
  float pe = se.x * we.x + se.y * we.y;
  #pragma unroll
  for (int off = 32; off; off >>= 1) { ps += __shfl_xor(ps, off); pe += __shfl_xor(pe, off); }
  float s_stu = ps + bstu[0];
  float s_exer = pe + bexer[0];
  float ed = 10.f * sgm(disc[eid]);
  float2 cs = *(const float2*)(cstu + lane * 2);
  float2 ce = *(const float2*)(cexer + lane * 2);
  float2 knv = *(const float2*)(kn + (size_t)w * KK + lane * 2);
  float x0 = ed * (sgm(s_stu + cs.x) - sgm(s_exer + ce.x)) * knv.x;
  float x1 = ed * (sgm(s_stu + cs.y) - sgm(s_exer + ce.y)) * knv.y;
  float2 w3v = *(const float2*)(W3 + lane * 2);
  float px = x0 * w3v.x + x1 * w3v.y;
  #pragma unroll
  for (int off = 32; off; off >>= 1) px += __shfl_xor(px, off);
  if (lane == 0) out[w] = sgm(px + b3[0]);
}

// ---------------- host ----------------

extern "C" void kernel_launch(void* const* d_in, const int* in_sizes, int n_in,
                              void* d_out, int out_size, void* d_ws, size_t ws_size,
                              hipStream_t stream)
{
  const float* entity = (const float*)d_in[0];
  const float* gcnW   = (const float*)d_in[1];
  const float* gcnB   = (const float*)d_in[2];
  const float* disc   = (const float*)d_in[3];
  const float* Wstu   = (const float*)d_in[4];
  const float* bstu   = (const float*)d_in[5];
  const float* Wexer  = (const float*)d_in[6];
  const float* bexer  = (const float*)d_in[7];
  const float* W3     = (const float*)d_in[8];
  const float* b3     = (const float*)d_in[9];
  const float* kn     = (const float*)d_in[10];
  const int* exer_id  = (const int*)d_in[12];
  const int* history  = (const int*)d_in[14];
  const int* hlen     = (const int*)d_in[15];
  const int* s0 = (const int*)d_in[16], *dd0 = (const int*)d_in[17];
  const int* s1 = (const int*)d_in[18], *dd1 = (const int*)d_in[19];
  const int* s2 = (const int*)d_in[20], *dd2 = (const int*)d_in[21];

  char* ws = (char*)d_ws;
  size_t off = 0;
  auto take = [&](size_t bytes) -> char* {
    char* p = ws + off;
    off = (off + bytes + 255) & ~(size_t)255;
    return p;
  };
  u16*   xent  = (u16*)take(NKf * 2);
  u16*   hA    = (u16*)take(NKf * 2);
  u16*   hB    = (u16*)take(NKf * 2);
  float* Sx    = (float*)take(NKf * 4);
  float* Ss    = (float*)take(NKf * 4);
  u16*   agg   = (u16*)take((size_t)NN * K3 * 2);   // 12,681,216 B; aliased by slabs below
  float* semb  = (float*)take((size_t)BB * KK * 4);
  float* cstu  = (float*)take(KK * 4);
  float* cexer = (float*)take(KK * 4);
  u16*   Bsw   = (u16*)take((size_t)3 * 49152 * 2);
  float* bsum  = (float*)take((size_t)3 * KK * 4);
  u32*   degI  = (u32*)take((size_t)3 * NN * 4);
  float* rsdO  = (float*)take((size_t)3 * NN * 4);
  float* rsdI  = (float*)take((size_t)3 * NN * 4);
  u32*   rp    = (u32*)take((size_t)3 * (NN + 1) * 4);
  u32*   csrc  = (u32*)take((size_t)3 * EE * 4);
  float* cnorm = (float*)take((size_t)3 * EE * 4);
  // slabs alias agg (3*64*8256*4 * 2 == NN*K3*2 exactly); agg written only after scatter
  u32* slabO = (u32*)agg;
  u32* slabI = slabO + (size_t)3 * NB * NP;
  (void)ws_size; (void)in_sizes; (void)n_in; (void)out_size;

  k_hist<<<dim3(NB, 3), 256, 0, stream>>>(s0, dd0, s1, dd1, s2, dd2, slabO, slabI);
  k_reduce<<<dim3((NP + 255) / 256, 3), 256, 0, stream>>>(slabO, slabI, degI, rsdO, rsdI);
  k_exscan2<<<3, 1024, 0, stream>>>(degI, rp);
  k_scatter2<<<dim3(NB, 3), 256, 0, stream>>>(s0, dd0, s1, dd1, s2, dd2, slabI, rp,
                                              rsdO, rsdI, csrc, cnorm);
  k_cvt<<<(NN * KK / 8 + 255) / 256, 256, 0, stream>>>(entity, xent);
  k_prepB<<<72, 256, 0, stream>>>(gcnW, Bsw);
  k_prepbias<<<3, KK, 0, stream>>>(gcnB, bsum);

  const u16* xs[3] = {xent, hA, hB};
  u16* outs[3]     = {hA, hB, nullptr};
  const int modes[3] = {1, 2, 4 | 8};
  for (int l = 0; l < 3; ++l) {
    k_spmm<<<dim3(NN * 64 / 256, 3), 256, 0, stream>>>(xs[l], rp, csrc, cnorm, agg);
    k_gemm<<<NN / 32, 256, 0, stream>>>(agg, Bsw + (size_t)l * 49152, bsum + (size_t)l * KK,
                                        outs[l], entity, Sx, Ss, modes[l]);
  }

  k_stuemb<<<BB * 64 / 256, 256, 0, stream>>>(Ss, history, hlen, semb);
  k_cproj<<<KK * 64 / 256, 256, 0, stream>>>(Sx, Wstu, Wexer, cstu, cexer);
  k_final<<<BB * 64 / 256, 256, 0, stream>>>(Sx, semb, cstu, cexer, Wstu, Wexer, W3, disc,
                                             exer_id, kn, bstu, bexer, b3, (float*)d_out);
}

// Round 4
// 237.858 us; speedup vs baseline: 2.5979x; 1.0966x over previous
//
#include <hip/hip_runtime.h>

#define NN 16512      // N = K + EXER nodes
#define KK 128        // feature dim
#define K3 384        // 3 graphs concatenated along K
#define EE 262144     // edges per graph
#define BB 2048       // batch
#define HH 64         // history length
#define NKf ((size_t)NN * KK)
#define NB 64         // hist blocks per graph
#define EPB (EE / NB) // 4096 edges per block
#define NP (NN / 2)   // 8256 packed u16-pair counters

typedef unsigned int u32;
typedef unsigned short u16;
typedef short bf16x8 __attribute__((ext_vector_type(8)));
typedef float f32x4 __attribute__((ext_vector_type(4)));

__device__ __forceinline__ float sgm(float x) { return 1.0f / (1.0f + __expf(-x)); }

__device__ __forceinline__ u16 f2bf(float f) {          // round-to-nearest-even
  u32 u = __float_as_uint(f);
  u32 r = u + 0x7fffu + ((u >> 16) & 1u);
  return (u16)(r >> 16);
}
__device__ __forceinline__ float bflo(u32 p) { return __uint_as_float(p << 16); }
__device__ __forceinline__ float bfhi(u32 p) { return __uint_as_float(p & 0xffff0000u); }

// ---------------- graph preprocessing (atomic-free counting sort) ----------------

// per-block private LDS histograms -> global slabs (no global atomics)
__global__ __launch_bounds__(256) void k_hist(
    const int* __restrict__ s0, const int* __restrict__ d0,
    const int* __restrict__ s1, const int* __restrict__ d1,
    const int* __restrict__ s2, const int* __restrict__ d2,
    u32* __restrict__ slabO, u32* __restrict__ slabI) {
  int g = blockIdx.y, b = blockIdx.x;
  const int* src = g == 0 ? s0 : (g == 1 ? s1 : s2);
  const int* dst = g == 0 ? d0 : (g == 1 ? d1 : d2);
  __shared__ u32 hO[NP], hI[NP];
  for (int i = threadIdx.x; i < NP; i += 256) { hO[i] = 0; hI[i] = 0; }
  __syncthreads();
  int base = b * EPB;
  for (int i = threadIdx.x; i < EPB; i += 256) {
    int s = src[base + i], d = dst[base + i];
    atomicAdd(&hO[s >> 1], 1u << ((s & 1) * 16));
    atomicAdd(&hI[d >> 1], 1u << ((d & 1) * 16));
  }
  __syncthreads();
  u32* oO = slabO + ((size_t)g * NB + b) * NP;
  u32* oI = slabI + ((size_t)g * NB + b) * NP;
  for (int i = threadIdx.x; i < NP; i += 256) { oO[i] = hO[i]; oI[i] = hI[i]; }
}

// sum slabs -> degrees (+rsqrt tables); in-place turn in-slabs into per-block prefixes
__global__ void k_reduce(u32* __restrict__ slabO, u32* __restrict__ slabI,
                         u32* __restrict__ degI, float* __restrict__ rsdO,
                         float* __restrict__ rsdI) {
  int g = blockIdx.y;
  int t = blockIdx.x * 256 + threadIdx.x;
  if (t >= NP) return;
  u32* sO = slabO + (size_t)g * NB * NP + t;
  u32* sI = slabI + (size_t)g * NB * NP + t;
  u32 sumO = 0, pre = 0;
  #pragma unroll 8
  for (int b = 0; b < NB; ++b) sumO += sO[(size_t)b * NP];
  #pragma unroll 8
  for (int b = 0; b < NB; ++b) {
    u32 v = sI[(size_t)b * NP];
    sI[(size_t)b * NP] = pre;          // packed u16 exclusive prefix (no overflow: deg small)
    pre += v;
  }
  u32 dOl = sumO & 0xffffu, dOh = sumO >> 16;
  u32 dIl = pre & 0xffffu,  dIh = pre >> 16;
  *(uint2*)(degI + (size_t)g * NN + 2 * t) = make_uint2(dIl, dIh);
  *(float2*)(rsdO + (size_t)g * NN + 2 * t) =
      make_float2(rsqrtf((float)(dOl ? dOl : 1u)), rsqrtf((float)(dOh ? dOh : 1u)));
  *(float2*)(rsdI + (size_t)g * NN + 2 * t) =
      make_float2(rsqrtf((float)(dIl ? dIl : 1u)), rsqrtf((float)(dIh ? dIh : 1u)));
}

// exclusive scan of in-degrees -> row_ptr; one block per graph
__global__ __launch_bounds__(1024) void k_exscan2(const u32* __restrict__ degI,
                                                  u32* __restrict__ rps) {
  int g = blockIdx.x;
  const u32* deg = degI + (size_t)g * NN;
  u32* rp = rps + (size_t)g * (NN + 1);
  int t = threadIdx.x;
  int i0 = t * 17, i1 = i0 + 17 < NN ? i0 + 17 : NN;
  u32 s = 0;
  for (int i = i0; i < i1; ++i) s += deg[i];
  u32 x = s;
  int lane = t & 63, wid = t >> 6;
  #pragma unroll
  for (int off = 1; off < 64; off <<= 1) {
    u32 y = __shfl_up(x, off);
    if (lane >= off) x += y;
  }
  __shared__ u32 wsums[16];
  if (lane == 63) wsums[wid] = x;
  __syncthreads();
  if (t == 0) {
    u32 run = 0;
    #pragma unroll
    for (int i = 0; i < 16; ++i) { u32 tmp = wsums[i]; wsums[i] = run; run += tmp; }
  }
  __syncthreads();
  u32 run = wsums[wid] + x - s;     // exclusive prefix for this thread
  for (int i = i0; i < i1; ++i) { rp[i] = run; run += deg[i]; }
  if (t == 0) rp[NN] = EE;
}

// place edges: LDS cursor = rp + per-block prefix; LDS atomics only, plain global stores
// edata[idx] = { src, norm(f32) } packed -> single 8B store per edge
__global__ __launch_bounds__(256) void k_scatter2(
    const int* __restrict__ s0, const int* __restrict__ d0,
    const int* __restrict__ s1, const int* __restrict__ d1,
    const int* __restrict__ s2, const int* __restrict__ d2,
    const u32* __restrict__ slabI, const u32* __restrict__ rps,
    const float* __restrict__ rsdO, const float* __restrict__ rsdI,
    uint2* __restrict__ edatas) {
  int g = blockIdx.y, b = blockIdx.x;
  const int* src = g == 0 ? s0 : (g == 1 ? s1 : s2);
  const int* dst = g == 0 ? d0 : (g == 1 ? d1 : d2);
  const u32* rp = rps + (size_t)g * (NN + 1);
  const u32* pre = slabI + ((size_t)g * NB + b) * NP;
  const float* rO = rsdO + (size_t)g * NN;
  const float* rI = rsdI + (size_t)g * NN;
  uint2* ed = edatas + (size_t)g * EE;
  __shared__ u32 cur[NN];
  for (int i = threadIdx.x; i < NP; i += 256) {
    u32 p = pre[i];
    cur[2 * i]     = rp[2 * i] + (p & 0xffffu);
    cur[2 * i + 1] = rp[2 * i + 1] + (p >> 16);
  }
  __syncthreads();
  int base = b * EPB;
  for (int i = threadIdx.x; i < EPB; i += 256) {
    int s = src[base + i], d = dst[base + i];
    u32 idx = atomicAdd(&cur[d], 1u);
    ed[idx] = make_uint2((u32)s, __float_as_uint(rO[s] * rI[d]));
  }
}

// ---------------- weight pre-swizzle into MFMA B-fragment order ----------------
// Bsw[((l*96 + nb*12 + ks)*64 + lane)*8 + j] = bf16( W[l, g, kin, kout] )
//   k = ks*32 + (lane>>4)*8 + j ; g = k>>7 ; kin = k&127 ; kout = nb*16 + (lane&15)

__global__ void k_prepB(const float* __restrict__ W, u16* __restrict__ Bsw) {
  int t = blockIdx.x * 256 + threadIdx.x;   // 0 .. 18431
  if (t >= 3 * 8 * 12 * 64) return;
  int lane = t & 63;
  int ks = (t >> 6) % 12;
  int nb = ((t >> 6) / 12) % 8;
  int l  = (t >> 6) / 96;
  int kout = nb * 16 + (lane & 15);
  int kb = ks * 32 + (lane >> 4) * 8;
  bf16x8 v;
  #pragma unroll
  for (int j = 0; j < 8; ++j) {
    int k = kb + j; int g = k >> 7; int kin = k & 127;
    v[j] = (short)f2bf(W[(((size_t)l * 3 + g) * KK + kin) * KK + kout]);
  }
  *(bf16x8*)(Bsw + (size_t)t * 8) = v;
}

__global__ void k_prepbias(const float* __restrict__ b, float* __restrict__ bsum) {
  int l = blockIdx.x, c = threadIdx.x;
  bsum[l * KK + c] = b[(l * 3 + 0) * KK + c] + b[(l * 3 + 1) * KK + c] + b[(l * 3 + 2) * KK + c];
}

__global__ void k_cvt(const float* __restrict__ in, u16* __restrict__ out) {
  int t = blockIdx.x * 256 + threadIdx.x;   // NN*KK/8 threads
  if (t >= NN * KK / 8) return;
  const float4* p = (const float4*)in + (size_t)t * 2;
  float4 v0 = p[0], v1 = p[1];
  bf16x8 o;
  o[0] = (short)f2bf(v0.x); o[1] = (short)f2bf(v0.y);
  o[2] = (short)f2bf(v0.z); o[3] = (short)f2bf(v0.w);
  o[4] = (short)f2bf(v1.x); o[5] = (short)f2bf(v1.y);
  o[6] = (short)f2bf(v1.z); o[7] = (short)f2bf(v1.w);
  *(bf16x8*)(out + (size_t)t * 8) = o;
}

// ---------------- SpMM: quad-edge wave layout ----------------
// lane = slot*16 + cg ; 16 lanes x 16B cover one 256B row; one wave-wide load = 4 edges.

__global__ __launch_bounds__(256) void k_spmm(const u16* __restrict__ x,
                                              const u32* __restrict__ rps,
                                              const uint2* __restrict__ edatas,
                                              u16* __restrict__ agg) {
  int g = blockIdx.y;
  const u32* rp = rps + (size_t)g * (NN + 1);
  const uint2* ed = edatas + (size_t)g * EE;
  int w = (blockIdx.x * 256 + threadIdx.x) >> 6;
  int lane = threadIdx.x & 63;
  if (w >= NN) return;
  w = __builtin_amdgcn_readfirstlane(w);     // wave-uniform
  const int slot = lane >> 4;                // edge within quad
  const int cg = lane & 15;                  // 16B column chunk
  u32 beg = rp[w], end = rp[w + 1];
  float acc[8] = {0.f, 0.f, 0.f, 0.f, 0.f, 0.f, 0.f, 0.f};
  u32 e = beg;
  for (; e + 4 <= end; e += 4) {
    uint2 m = ed[e + slot];
    float n = __uint_as_float(m.y);
    uint4 p = *(const uint4*)(x + (size_t)m.x * KK + cg * 8);
    acc[0] += bflo(p.x) * n; acc[1] += bfhi(p.x) * n;
    acc[2] += bflo(p.y) * n; acc[3] += bfhi(p.y) * n;
    acc[4] += bflo(p.z) * n; acc[5] += bfhi(p.z) * n;
    acc[6] += bflo(p.w) * n; acc[7] += bfhi(p.w) * n;
  }
  if (e + slot < end) {                      // masked tail (up to 3 edges)
    uint2 m = ed[e + slot];
    float n = __uint_as_float(m.y);
    uint4 p = *(const uint4*)(x + (size_t)m.x * KK + cg * 8);
    acc[0] += bflo(p.x) * n; acc[1] += bfhi(p.x) * n;
    acc[2] += bflo(p.y) * n; acc[3] += bfhi(p.y) * n;
    acc[4] += bflo(p.z) * n; acc[5] += bfhi(p.z) * n;
    acc[6] += bflo(p.w) * n; acc[7] += bfhi(p.w) * n;
  }
  #pragma unroll
  for (int i = 0; i < 8; ++i) {              // reduce across the 4 slots
    acc[i] += __shfl_xor(acc[i], 16);
    acc[i] += __shfl_xor(acc[i], 32);
  }
  if (slot == 0) {
    u32 o0 = ((u32)f2bf(acc[1]) << 16) | (u32)f2bf(acc[0]);
    u32 o1 = ((u32)f2bf(acc[3]) << 16) | (u32)f2bf(acc[2]);
    u32 o2 = ((u32)f2bf(acc[5]) << 16) | (u32)f2bf(acc[4]);
    u32 o3 = ((u32)f2bf(acc[7]) << 16) | (u32)f2bf(acc[6]);
    *(uint4*)(agg + (size_t)w * K3 + g * KK + cg * 8) = make_uint4(o0, o1, o2, o3);
  }
}

// ---------------- MFMA GEMM: h = agg[M,384] @ B[384,128] + bsum, fused epilogue ----------
// mode: 1 = Sx = entity + v ; else Sx += v
//       2 = Ss = v ; 4 = Ss += v ; 8 = skip h write

__global__ __launch_bounds__(256) void k_gemm(
    const u16* __restrict__ agg, const u16* __restrict__ Bsw, const float* __restrict__ bsum,
    u16* __restrict__ hout, const float* __restrict__ entity,
    float* __restrict__ Sx, float* __restrict__ Ss, int mode)
{
  const int tid = threadIdx.x;
  const int wv = tid >> 6, lane = tid & 63;
  const int m0 = blockIdx.x * 32;
  const int n0 = wv * 32;
  const int lr = lane & 15;        // A row-in-frag / B,C col
  const int lk = lane >> 4;        // k-group of 8

  f32x4 z = {0.f, 0.f, 0.f, 0.f};
  f32x4 acc[2][2] = {{z, z}, {z, z}};

  const u16* aA = agg + (size_t)(m0 + lr) * K3 + lk * 8;            // +i*16*384, +ks*32
  const u16* aB = Bsw + (size_t)(wv * 2) * 6144 + (size_t)lane * 8; // +j*6144, +ks*512

  #pragma unroll
  for (int ks = 0; ks < 12; ++ks) {
    bf16x8 a0 = *(const bf16x8*)(aA + ks * 32);
    bf16x8 a1 = *(const bf16x8*)(aA + 16 * K3 + ks * 32);
    bf16x8 b0 = *(const bf16x8*)(aB + ks * 512);
    bf16x8 b1 = *(const bf16x8*)(aB + 6144 + ks * 512);
    acc[0][0] = __builtin_amdgcn_mfma_f32_16x16x32_bf16(a0, b0, acc[0][0], 0, 0, 0);
    acc[0][1] = __builtin_amdgcn_mfma_f32_16x16x32_bf16(a0, b1, acc[0][1], 0, 0, 0);
    acc[1][0] = __builtin_amdgcn_mfma_f32_16x16x32_bf16(a1, b0, acc[1][0], 0, 0, 0);
    acc[1][1] = __builtin_amdgcn_mfma_f32_16x16x32_bf16(a1, b1, acc[1][1], 0, 0, 0);
  }

  #pragma unroll
  for (int j = 0; j < 2; ++j) {
    int col = n0 + j * 16 + lr;
    float bv = bsum[col];
    #pragma unroll
    for (int i = 0; i < 2; ++i) {
      int rowb = m0 + i * 16 + lk * 4;
      #pragma unroll
      for (int r = 0; r < 4; ++r) {
        size_t idx = (size_t)(rowb + r) * KK + col;
        float v = acc[i][j][r] + bv;
        if (!(mode & 8)) hout[idx] = f2bf(v);
        float sx = (mode & 1) ? (entity[idx] + v) : (Sx[idx] + v);
        Sx[idx] = sx;
        if (mode & 2) Ss[idx] = v;
        else if (mode & 4) Ss[idx] += v;
      }
    }
  }
}

// ---------------- downstream ----------------

__global__ void k_stuemb(const float* __restrict__ Ss, const int* __restrict__ hist,
                         const int* __restrict__ hlen, float* __restrict__ semb) {
  int w = (blockIdx.x * 256 + threadIdx.x) >> 6;
  int lane = threadIdx.x & 63;
  if (w >= BB) return;
  int len = hlen[w];
  float2 acc = make_float2(0.f, 0.f);
  for (int h = 0; h < len; ++h) {
    int id = hist[w * HH + h];
    float2 v = *(const float2*)(Ss + ((size_t)(KK + id)) * KK + lane * 2);
    acc.x += v.x; acc.y += v.y;
  }
  float sc = 0.5f / (float)len;   // stu_entity = 0.5 * Ss, then / len
  *(float2*)(semb + (size_t)w * KK + lane * 2) = make_float2(acc.x * sc, acc.y * sc);
}

__global__ void k_cproj(const float* __restrict__ Sx, const float* __restrict__ Wstu,
                        const float* __restrict__ Wexer, float* __restrict__ cstu,
                        float* __restrict__ cexer) {
  int w = (blockIdx.x * 256 + threadIdx.x) >> 6;   // concept row j
  int lane = threadIdx.x & 63;
  if (w >= KK) return;
  float2 c = *(const float2*)(Sx + (size_t)w * KK + lane * 2);
  c.x *= 0.25f; c.y *= 0.25f;
  float2 ws = *(const float2*)(Wstu + KK + lane * 2);
  float2 we = *(const float2*)(Wexer + KK + lane * 2);
  float ps = c.x * ws.x + c.y * ws.y;
  float pe = c.x * we.x + c.y * we.y;
  #pragma unroll
  for (int off = 32; off; off >>= 1) { ps += __shfl_xor(ps, off); pe += __shfl_xor(pe, off); }
  if (lane == 0) { cstu[w] = ps; cexer[w] = pe; }
}

__global__ void k_final(const float* __restrict__ Sx, const float* __restrict__ semb,
                        const float* __restrict__ cstu, const float* __restrict__ cexer,
                        const float* __restrict__ Wstu, const float* __restrict__ Wexer,
                        const float* __restrict__ W3, const float* __restrict__ disc,
                        const int* __restrict__ exid, const float* __restrict__ kn,
                        const float* __restrict__ bstu, const float* __restrict__ bexer,
                        const float* __restrict__ b3, float* __restrict__ out) {
  int w = (blockIdx.x * 256 + threadIdx.x) >> 6;   // batch index
  int lane = threadIdx.x & 63;
  if (w >= BB) return;
  int eid = exid[w];
  float2 se = *(const float2*)(Sx + ((size_t)(KK + eid)) * KK + lane * 2);
  se.x *= 0.25f; se.y *= 0.25f;                    // exer_emb
  float2 sm = *(const float2*)(semb + (size_t)w * KK + lane * 2);
  float2 ws = *(const float2*)(Wstu + lane * 2);
  float2 we = *(const float2*)(Wexer + lane * 2);
  float ps = sm.x * ws.x + sm.y * ws.y;
  float pe = se.x * we.x + se.y * we.y;
  #pragma unroll
  for (int off = 32; off; off >>= 1) { ps += __shfl_xor(ps, off); pe += __shfl_xor(pe, off); }
  float s_stu = ps + bstu[0];
  float s_exer = pe + bexer[0];
  float ed = 10.f * sgm(disc[eid]);
  float2 cs = *(const float2*)(cstu + lane * 2);
  float2 ce = *(const float2*)(cexer + lane * 2);
  float2 knv = *(const float2*)(kn + (size_t)w * KK + lane * 2);
  float x0 = ed * (sgm(s_stu + cs.x) - sgm(s_exer + ce.x)) * knv.x;
  float x1 = ed * (sgm(s_stu + cs.y) - sgm(s_exer + ce.y)) * knv.y;
  float2 w3v = *(const float2*)(W3 + lane * 2);
  float px = x0 * w3v.x + x1 * w3v.y;
  #pragma unroll
  for (int off = 32; off; off >>= 1) px += __shfl_xor(px, off);
  if (lane == 0) out[w] = sgm(px + b3[0]);
}

// ---------------- host ----------------

extern "C" void kernel_launch(void* const* d_in, const int* in_sizes, int n_in,
                              void* d_out, int out_size, void* d_ws, size_t ws_size,
                              hipStream_t stream)
{
  const float* entity = (const float*)d_in[0];
  const float* gcnW   = (const float*)d_in[1];
  const float* gcnB   = (const float*)d_in[2];
  const float* disc   = (const float*)d_in[3];
  const float* Wstu   = (const float*)d_in[4];
  const float* bstu   = (const float*)d_in[5];
  const float* Wexer  = (const float*)d_in[6];
  const float* bexer  = (const float*)d_in[7];
  const float* W3     = (const float*)d_in[8];
  const float* b3     = (const float*)d_in[9];
  const float* kn     = (const float*)d_in[10];
  const int* exer_id  = (const int*)d_in[12];
  const int* history  = (const int*)d_in[14];
  const int* hlen     = (const int*)d_in[15];
  const int* s0 = (const int*)d_in[16], *dd0 = (const int*)d_in[17];
  const int* s1 = (const int*)d_in[18], *dd1 = (const int*)d_in[19];
  const int* s2 = (const int*)d_in[20], *dd2 = (const int*)d_in[21];

  char* ws = (char*)d_ws;
  size_t off = 0;
  auto take = [&](size_t bytes) -> char* {
    char* p = ws + off;
    off = (off + bytes + 255) & ~(size_t)255;
    return p;
  };
  u16*   xent  = (u16*)take(NKf * 2);
  u16*   hA    = (u16*)take(NKf * 2);
  u16*   hB    = (u16*)take(NKf * 2);
  float* Sx    = (float*)take(NKf * 4);
  float* Ss    = (float*)take(NKf * 4);
  u16*   agg   = (u16*)take((size_t)NN * K3 * 2);   // aliased by slabs below
  float* semb  = (float*)take((size_t)BB * KK * 4);
  float* cstu  = (float*)take(KK * 4);
  float* cexer = (float*)take(KK * 4);
  u16*   Bsw   = (u16*)take((size_t)3 * 49152 * 2);
  float* bsum  = (float*)take((size_t)3 * KK * 4);
  u32*   degI  = (u32*)take((size_t)3 * NN * 4);
  float* rsdO  = (float*)take((size_t)3 * NN * 4);
  float* rsdI  = (float*)take((size_t)3 * NN * 4);
  u32*   rp    = (u32*)take((size_t)3 * (NN + 1) * 4);
  uint2* edata = (uint2*)take((size_t)3 * EE * 8);
  // slabs alias agg (3*64*8256*4 * 2 == NN*K3*2 exactly); agg written only after scatter
  u32* slabO = (u32*)agg;
  u32* slabI = slabO + (size_t)3 * NB * NP;
  (void)ws_size; (void)in_sizes; (void)n_in; (void)out_size;

  k_hist<<<dim3(NB, 3), 256, 0, stream>>>(s0, dd0, s1, dd1, s2, dd2, slabO, slabI);
  k_reduce<<<dim3((NP + 255) / 256, 3), 256, 0, stream>>>(slabO, slabI, degI, rsdO, rsdI);
  k_exscan2<<<3, 1024, 0, stream>>>(degI, rp);
  k_scatter2<<<dim3(NB, 3), 256, 0, stream>>>(s0, dd0, s1, dd1, s2, dd2, slabI, rp,
                                              rsdO, rsdI, edata);
  k_cvt<<<(NN * KK / 8 + 255) / 256, 256, 0, stream>>>(entity, xent);
  k_prepB<<<72, 256, 0, stream>>>(gcnW, Bsw);
  k_prepbias<<<3, KK, 0, stream>>>(gcnB, bsum);

  const u16* xs[3] = {xent, hA, hB};
  u16* outs[3]     = {hA, hB, nullptr};
  const int modes[3] = {1, 2, 4 | 8};
  for (int l = 0; l < 3; ++l) {
    k_spmm<<<dim3(NN * 64 / 256, 3), 256, 0, stream>>>(xs[l], rp, edata, agg);
    k_gemm<<<NN / 32, 256, 0, stream>>>(agg, Bsw + (size_t)l * 49152, bsum + (size_t)l * KK,
                                        outs[l], entity, Sx, Ss, modes[l]);
  }

  k_stuemb<<<BB * 64 / 256, 256, 0, stream>>>(Ss, history, hlen, semb);
  k_cproj<<<KK * 64 / 256, 256, 0, stream>>>(Sx, Wstu, Wexer, cstu, cexer);
  k_final<<<BB * 64 / 256, 256, 0, stream>>>(Sx, semb, cstu, cexer, Wstu, Wexer, W3, disc,
                                             exer_id, kn, bstu, bexer, b3, (float*)d_out);
}

// Round 5
// 233.538 us; speedup vs baseline: 2.6460x; 1.0185x over previous
//
#include <hip/hip_runtime.h>

#define NN 16512      // N = K + EXER nodes
#define KK 128        // feature dim
#define K3 384        // 3 graphs concatenated along K
#define EE 262144     // edges per graph
#define BB 2048       // batch
#define HH 64         // history length
#define NKf ((size_t)NN * KK)
#define NB 64         // hist blocks per graph
#define EPB (EE / NB) // 4096 edges per block
#define NP (NN / 2)   // 8256 packed u16-pair counters

typedef unsigned int u32;
typedef unsigned short u16;
typedef short bf16x8 __attribute__((ext_vector_type(8)));
typedef float f32x4 __attribute__((ext_vector_type(4)));

__device__ __forceinline__ float sgm(float x) { return 1.0f / (1.0f + __expf(-x)); }

__device__ __forceinline__ u16 f2bf(float f) {          // round-to-nearest-even
  u32 u = __float_as_uint(f);
  u32 r = u + 0x7fffu + ((u >> 16) & 1u);
  return (u16)(r >> 16);
}
__device__ __forceinline__ float bflo(u32 p) { return __uint_as_float(p << 16); }
__device__ __forceinline__ float bfhi(u32 p) { return __uint_as_float(p & 0xffff0000u); }

// ---------------- graph preprocessing (atomic-free counting sort) ----------------

__global__ __launch_bounds__(256) void k_hist(
    const int* __restrict__ s0, const int* __restrict__ d0,
    const int* __restrict__ s1, const int* __restrict__ d1,
    const int* __restrict__ s2, const int* __restrict__ d2,
    u32* __restrict__ slabO, u32* __restrict__ slabI) {
  int g = blockIdx.y, b = blockIdx.x;
  const int* src = g == 0 ? s0 : (g == 1 ? s1 : s2);
  const int* dst = g == 0 ? d0 : (g == 1 ? d1 : d2);
  __shared__ u32 hO[NP], hI[NP];
  for (int i = threadIdx.x; i < NP; i += 256) { hO[i] = 0; hI[i] = 0; }
  __syncthreads();
  int base = b * EPB;
  for (int i = threadIdx.x; i < EPB; i += 256) {
    int s = src[base + i], d = dst[base + i];
    atomicAdd(&hO[s >> 1], 1u << ((s & 1) * 16));
    atomicAdd(&hI[d >> 1], 1u << ((d & 1) * 16));
  }
  __syncthreads();
  u32* oO = slabO + ((size_t)g * NB + b) * NP;
  u32* oI = slabI + ((size_t)g * NB + b) * NP;
  for (int i = threadIdx.x; i < NP; i += 256) { oO[i] = hO[i]; oI[i] = hI[i]; }
}

__global__ void k_reduce(u32* __restrict__ slabO, u32* __restrict__ slabI,
                         u32* __restrict__ degI, float* __restrict__ rsdO,
                         float* __restrict__ rsdI) {
  int g = blockIdx.y;
  int t = blockIdx.x * 256 + threadIdx.x;
  if (t >= NP) return;
  u32* sO = slabO + (size_t)g * NB * NP + t;
  u32* sI = slabI + (size_t)g * NB * NP + t;
  u32 sumO = 0, pre = 0;
  #pragma unroll 8
  for (int b = 0; b < NB; ++b) sumO += sO[(size_t)b * NP];
  #pragma unroll 8
  for (int b = 0; b < NB; ++b) {
    u32 v = sI[(size_t)b * NP];
    sI[(size_t)b * NP] = pre;          // packed u16 exclusive prefix
    pre += v;
  }
  u32 dOl = sumO & 0xffffu, dOh = sumO >> 16;
  u32 dIl = pre & 0xffffu,  dIh = pre >> 16;
  *(uint2*)(degI + (size_t)g * NN + 2 * t) = make_uint2(dIl, dIh);
  *(float2*)(rsdO + (size_t)g * NN + 2 * t) =
      make_float2(rsqrtf((float)(dOl ? dOl : 1u)), rsqrtf((float)(dOh ? dOh : 1u)));
  *(float2*)(rsdI + (size_t)g * NN + 2 * t) =
      make_float2(rsqrtf((float)(dIl ? dIl : 1u)), rsqrtf((float)(dIh ? dIh : 1u)));
}

__global__ __launch_bounds__(1024) void k_exscan2(const u32* __restrict__ degI,
                                                  u32* __restrict__ rps) {
  int g = blockIdx.x;
  const u32* deg = degI + (size_t)g * NN;
  u32* rp = rps + (size_t)g * (NN + 1);
  int t = threadIdx.x;
  int i0 = t * 17, i1 = i0 + 17 < NN ? i0 + 17 : NN;
  u32 s = 0;
  for (int i = i0; i < i1; ++i) s += deg[i];
  u32 x = s;
  int lane = t & 63, wid = t >> 6;
  #pragma unroll
  for (int off = 1; off < 64; off <<= 1) {
    u32 y = __shfl_up(x, off);
    if (lane >= off) x += y;
  }
  __shared__ u32 wsums[16];
  if (lane == 63) wsums[wid] = x;
  __syncthreads();
  if (t == 0) {
    u32 run = 0;
    #pragma unroll
    for (int i = 0; i < 16; ++i) { u32 tmp = wsums[i]; wsums[i] = run; run += tmp; }
  }
  __syncthreads();
  u32 run = wsums[wid] + x - s;
  for (int i = i0; i < i1; ++i) { rp[i] = run; run += deg[i]; }
  if (t == 0) rp[NN] = EE;
}

// edata[idx] = { src, norm(f32) } -> single 8B store per edge
__global__ __launch_bounds__(256) void k_scatter2(
    const int* __restrict__ s0, const int* __restrict__ d0,
    const int* __restrict__ s1, const int* __restrict__ d1,
    const int* __restrict__ s2, const int* __restrict__ d2,
    const u32* __restrict__ slabI, const u32* __restrict__ rps,
    const float* __restrict__ rsdO, const float* __restrict__ rsdI,
    uint2* __restrict__ edatas) {
  int g = blockIdx.y, b = blockIdx.x;
  const int* src = g == 0 ? s0 : (g == 1 ? s1 : s2);
  const int* dst = g == 0 ? d0 : (g == 1 ? d1 : d2);
  const u32* rp = rps + (size_t)g * (NN + 1);
  const u32* pre = slabI + ((size_t)g * NB + b) * NP;
  const float* rO = rsdO + (size_t)g * NN;
  const float* rI = rsdI + (size_t)g * NN;
  uint2* ed = edatas + (size_t)g * EE;
  __shared__ u32 cur[NN];
  for (int i = threadIdx.x; i < NP; i += 256) {
    u32 p = pre[i];
    cur[2 * i]     = rp[2 * i] + (p & 0xffffu);
    cur[2 * i + 1] = rp[2 * i + 1] + (p >> 16);
  }
  __syncthreads();
  int base = b * EPB;
  for (int i = threadIdx.x; i < EPB; i += 256) {
    int s = src[base + i], d = dst[base + i];
    u32 idx = atomicAdd(&cur[d], 1u);
    ed[idx] = make_uint2((u32)s, __float_as_uint(rO[s] * rI[d]));
  }
}

// ---------------- fused prep: entity->bf16 | W pre-swizzle | bias sums ----------------
// Bsw[((l*96 + nb*12 + ks)*64 + lane)*8 + j] = bf16( W[l, g, kin, kout] )
//   k = ks*32 + (lane>>4)*8 + j ; g = k>>7 ; kin = k&127 ; kout = nb*16 + (lane&15)

__global__ void k_prep(const float* __restrict__ entity, u16* __restrict__ xent,
                       const float* __restrict__ W, u16* __restrict__ Bsw,
                       const float* __restrict__ b, float* __restrict__ bsum) {
  int bid = blockIdx.x;
  if (bid < 1032) {                       // cvt: NN*KK/8 = 264192 items
    int t = bid * 256 + threadIdx.x;
    if (t >= NN * KK / 8) return;
    const float4* p = (const float4*)entity + (size_t)t * 2;
    float4 v0 = p[0], v1 = p[1];
    bf16x8 o;
    o[0] = (short)f2bf(v0.x); o[1] = (short)f2bf(v0.y);
    o[2] = (short)f2bf(v0.z); o[3] = (short)f2bf(v0.w);
    o[4] = (short)f2bf(v1.x); o[5] = (short)f2bf(v1.y);
    o[6] = (short)f2bf(v1.z); o[7] = (short)f2bf(v1.w);
    *(bf16x8*)(xent + (size_t)t * 8) = o;
  } else if (bid < 1104) {                // prepB: 18432 items
    int t = (bid - 1032) * 256 + threadIdx.x;
    if (t >= 3 * 8 * 12 * 64) return;
    int lane = t & 63;
    int ks = (t >> 6) % 12;
    int nb = ((t >> 6) / 12) % 8;
    int l  = (t >> 6) / 96;
    int kout = nb * 16 + (lane & 15);
    int kb = ks * 32 + (lane >> 4) * 8;
    bf16x8 v;
    #pragma unroll
    for (int j = 0; j < 8; ++j) {
      int k = kb + j; int g = k >> 7; int kin = k & 127;
      v[j] = (short)f2bf(W[(((size_t)l * 3 + g) * KK + kin) * KK + kout]);
    }
    *(bf16x8*)(Bsw + (size_t)t * 8) = v;
  } else {                                // bias sums: 384 items
    int t = (bid - 1104) * 256 + threadIdx.x;
    if (t >= 3 * KK) return;
    int l = t >> 7, c = t & 127;
    bsum[l * KK + c] = b[(l * 3 + 0) * KK + c] + b[(l * 3 + 1) * KK + c] + b[(l * 3 + 2) * KK + c];
  }
}

// ---------------- fused layer: SpMM (3 graphs -> LDS) + MFMA GEMM + epilogue ----------
// Block owns 32 rows. 8 waves. SpMM tasks t=(g<<5)|row, quad-edge layout.
// mode: 1 = Sx = entity + v ; else Sx += v
//       2 = Ss = v ; 4 = Ssb = bf16(Ss + v) ; 8 = skip h write

__global__ __launch_bounds__(512) void k_layer(
    const u16* __restrict__ x, const u32* __restrict__ rps,
    const uint2* __restrict__ edatas, const u16* __restrict__ Bsw,
    const float* __restrict__ bsum, u16* __restrict__ hout,
    const float* __restrict__ entity, float* __restrict__ Sx,
    float* __restrict__ Ss, u16* __restrict__ Ssb, int mode)
{
  __shared__ u16 At[32][392];             // 24.5 KB, row stride 784B = 4 banks -> 2-way (free)
  const int tid = threadIdx.x;
  const int wv = tid >> 6, lane = tid & 63;
  const int m0 = blockIdx.x * 32;
  const int slot = lane >> 4, cg = lane & 15;

  // ---- SpMM phase ----
  for (int t = wv; t < 96; t += 8) {
    int g = t >> 5, r = t & 31;
    const u32* rp = rps + (size_t)g * (NN + 1) + (m0 + r);
    const uint2* ed = edatas + (size_t)g * EE;
    u32 beg = rp[0], end = rp[1];
    float acc[8] = {0.f, 0.f, 0.f, 0.f, 0.f, 0.f, 0.f, 0.f};
    u32 e = beg;
    for (; e + 4 <= end; e += 4) {
      uint2 m = ed[e + slot];
      float n = __uint_as_float(m.y);
      uint4 p = *(const uint4*)(x + (size_t)m.x * KK + cg * 8);
      acc[0] += bflo(p.x) * n; acc[1] += bfhi(p.x) * n;
      acc[2] += bflo(p.y) * n; acc[3] += bfhi(p.y) * n;
      acc[4] += bflo(p.z) * n; acc[5] += bfhi(p.z) * n;
      acc[6] += bflo(p.w) * n; acc[7] += bfhi(p.w) * n;
    }
    if (e + slot < end) {
      uint2 m = ed[e + slot];
      float n = __uint_as_float(m.y);
      uint4 p = *(const uint4*)(x + (size_t)m.x * KK + cg * 8);
      acc[0] += bflo(p.x) * n; acc[1] += bfhi(p.x) * n;
      acc[2] += bflo(p.y) * n; acc[3] += bfhi(p.y) * n;
      acc[4] += bflo(p.z) * n; acc[5] += bfhi(p.z) * n;
      acc[6] += bflo(p.w) * n; acc[7] += bfhi(p.w) * n;
    }
    #pragma unroll
    for (int i = 0; i < 8; ++i) {
      acc[i] += __shfl_xor(acc[i], 16);
      acc[i] += __shfl_xor(acc[i], 32);
    }
    if (slot == 0) {
      u32 o0 = ((u32)f2bf(acc[1]) << 16) | (u32)f2bf(acc[0]);
      u32 o1 = ((u32)f2bf(acc[3]) << 16) | (u32)f2bf(acc[2]);
      u32 o2 = ((u32)f2bf(acc[5]) << 16) | (u32)f2bf(acc[4]);
      u32 o3 = ((u32)f2bf(acc[7]) << 16) | (u32)f2bf(acc[6]);
      *(uint4*)(&At[r][g * KK + cg * 8]) = make_uint4(o0, o1, o2, o3);
    }
  }
  __syncthreads();

  // ---- MFMA phase: 32x128 = At(32x384) @ B(384x128) ----
  const int mi = wv >> 2, ni = wv & 3;
  const int lr = lane & 15, lk = lane >> 4;
  f32x4 z = {0.f, 0.f, 0.f, 0.f};
  f32x4 acc2[2] = {z, z};
  const u16* aB = Bsw + (size_t)(ni * 2) * 6144 + (size_t)lane * 8;
  #pragma unroll
  for (int ks = 0; ks < 12; ++ks) {
    bf16x8 a  = *(const bf16x8*)(&At[mi * 16 + lr][ks * 32 + lk * 8]);
    bf16x8 b0 = *(const bf16x8*)(aB + ks * 512);
    bf16x8 b1 = *(const bf16x8*)(aB + 6144 + ks * 512);
    acc2[0] = __builtin_amdgcn_mfma_f32_16x16x32_bf16(a, b0, acc2[0], 0, 0, 0);
    acc2[1] = __builtin_amdgcn_mfma_f32_16x16x32_bf16(a, b1, acc2[1], 0, 0, 0);
  }

  #pragma unroll
  for (int jj = 0; jj < 2; ++jj) {
    int col = ni * 32 + jj * 16 + lr;
    float bv = bsum[col];
    int rowb = m0 + mi * 16 + lk * 4;
    #pragma unroll
    for (int r = 0; r < 4; ++r) {
      size_t idx = (size_t)(rowb + r) * KK + col;
      float v = acc2[jj][r] + bv;
      if (!(mode & 8)) hout[idx] = f2bf(v);
      float sx = (mode & 1) ? (entity[idx] + v) : (Sx[idx] + v);
      Sx[idx] = sx;
      if (mode & 2) Ss[idx] = v;
      else if (mode & 4) Ssb[idx] = f2bf(Ss[idx] + v);
    }
  }
}

// ---------------- fused post: history mean (quad rows) + concept projections ----------

__global__ __launch_bounds__(256) void k_post(
    const u16* __restrict__ Ssb, const int* __restrict__ hist, const int* __restrict__ hlen,
    float* __restrict__ semb, const float* __restrict__ Sx,
    const float* __restrict__ Wstu, const float* __restrict__ Wexer,
    float* __restrict__ cstu, float* __restrict__ cexer)
{
  int wv = threadIdx.x >> 6, lane = threadIdx.x & 63;
  if (blockIdx.x < 512) {                 // stuemb: 2048 items
    int item = blockIdx.x * 4 + wv;
    int slot = lane >> 4, cg = lane & 15;
    int len = hlen[item];
    const int* hrow = hist + item * HH;
    float acc[8] = {0.f, 0.f, 0.f, 0.f, 0.f, 0.f, 0.f, 0.f};
    int h = 0;
    for (; h + 4 <= len; h += 4) {
      int id = hrow[h + slot];
      uint4 p = *(const uint4*)(Ssb + (size_t)(KK + id) * KK + cg * 8);
      acc[0] += bflo(p.x); acc[1] += bfhi(p.x);
      acc[2] += bflo(p.y); acc[3] += bfhi(p.y);
      acc[4] += bflo(p.z); acc[5] += bfhi(p.z);
      acc[6] += bflo(p.w); acc[7] += bfhi(p.w);
    }
    if (h + slot < len) {
      int id = hrow[h + slot];
      uint4 p = *(const uint4*)(Ssb + (size_t)(KK + id) * KK + cg * 8);
      acc[0] += bflo(p.x); acc[1] += bfhi(p.x);
      acc[2] += bflo(p.y); acc[3] += bfhi(p.y);
      acc[4] += bflo(p.z); acc[5] += bfhi(p.z);
      acc[6] += bflo(p.w); acc[7] += bfhi(p.w);
    }
    #pragma unroll
    for (int i = 0; i < 8; ++i) {
      acc[i] += __shfl_xor(acc[i], 16);
      acc[i] += __shfl_xor(acc[i], 32);
    }
    if (slot == 0) {
      float sc = 0.5f / (float)len;
      float4 o0 = make_float4(acc[0] * sc, acc[1] * sc, acc[2] * sc, acc[3] * sc);
      float4 o1 = make_float4(acc[4] * sc, acc[5] * sc, acc[6] * sc, acc[7] * sc);
      *(float4*)(semb + (size_t)item * KK + cg * 8) = o0;
      *(float4*)(semb + (size_t)item * KK + cg * 8 + 4) = o1;
    }
  } else {                                // cproj: 128 concept rows
    int w = (blockIdx.x - 512) * 4 + wv;
    float2 c = *(const float2*)(Sx + (size_t)w * KK + lane * 2);
    c.x *= 0.25f; c.y *= 0.25f;
    float2 ws = *(const float2*)(Wstu + KK + lane * 2);
    float2 we = *(const float2*)(Wexer + KK + lane * 2);
    float ps = c.x * ws.x + c.y * ws.y;
    float pe = c.x * we.x + c.y * we.y;
    #pragma unroll
    for (int off = 32; off; off >>= 1) { ps += __shfl_xor(ps, off); pe += __shfl_xor(pe, off); }
    if (lane == 0) { cstu[w] = ps; cexer[w] = pe; }
  }
}

__global__ void k_final(const float* __restrict__ Sx, const float* __restrict__ semb,
                        const float* __restrict__ cstu, const float* __restrict__ cexer,
                        const float* __restrict__ Wstu, const float* __restrict__ Wexer,
                        const float* __restrict__ W3, const float* __restrict__ disc,
                        const int* __restrict__ exid, const float* __restrict__ kn,
                        const float* __restrict__ bstu, const float* __restrict__ bexer,
                        const float* __restrict__ b3, float* __restrict__ out) {
  int w = (blockIdx.x * 256 + threadIdx.x) >> 6;   // batch index
  int lane = threadIdx.x & 63;
  if (w >= BB) return;
  int eid = exid[w];
  float2 se = *(const float2*)(Sx + ((size_t)(KK + eid)) * KK + lane * 2);
  se.x *= 0.25f; se.y *= 0.25f;                    // exer_emb
  float2 sm = *(const float2*)(semb + (size_t)w * KK + lane * 2);
  float2 ws = *(const float2*)(Wstu + lane * 2);
  float2 we = *(const float2*)(Wexer + lane * 2);
  float ps = sm.x * ws.x + sm.y * ws.y;
  float pe = se.x * we.x + se.y * we.y;
  #pragma unroll
  for (int off = 32; off; off >>= 1) { ps += __shfl_xor(ps, off); pe += __shfl_xor(pe, off); }
  float s_stu = ps + bstu[0];
  float s_exer = pe + bexer[0];
  float ed = 10.f * sgm(disc[eid]);
  float2 cs = *(const float2*)(cstu + lane * 2);
  float2 ce = *(const float2*)(cexer + lane * 2);
  float2 knv = *(const float2*)(kn + (size_t)w * KK + lane * 2);
  float x0 = ed * (sgm(s_stu + cs.x) - sgm(s_exer + ce.x)) * knv.x;
  float x1 = ed * (sgm(s_stu + cs.y) - sgm(s_exer + ce.y)) * knv.y;
  float2 w3v = *(const float2*)(W3 + lane * 2);
  float px = x0 * w3v.x + x1 * w3v.y;
  #pragma unroll
  for (int off = 32; off; off >>= 1) px += __shfl_xor(px, off);
  if (lane == 0) out[w] = sgm(px + b3[0]);
}

// ---------------- host ----------------

extern "C" void kernel_launch(void* const* d_in, const int* in_sizes, int n_in,
                              void* d_out, int out_size, void* d_ws, size_t ws_size,
                              hipStream_t stream)
{
  const float* entity = (const float*)d_in[0];
  const float* gcnW   = (const float*)d_in[1];
  const float* gcnB   = (const float*)d_in[2];
  const float* disc   = (const float*)d_in[3];
  const float* Wstu   = (const float*)d_in[4];
  const float* bstu   = (const float*)d_in[5];
  const float* Wexer  = (const float*)d_in[6];
  const float* bexer  = (const float*)d_in[7];
  const float* W3     = (const float*)d_in[8];
  const float* b3     = (const float*)d_in[9];
  const float* kn     = (const float*)d_in[10];
  const int* exer_id  = (const int*)d_in[12];
  const int* history  = (const int*)d_in[14];
  const int* hlen     = (const int*)d_in[15];
  const int* s0 = (const int*)d_in[16], *dd0 = (const int*)d_in[17];
  const int* s1 = (const int*)d_in[18], *dd1 = (const int*)d_in[19];
  const int* s2 = (const int*)d_in[20], *dd2 = (const int*)d_in[21];

  char* ws = (char*)d_ws;
  size_t off = 0;
  auto take = [&](size_t bytes) -> char* {
    char* p = ws + off;
    off = (off + bytes + 255) & ~(size_t)255;
    return p;
  };
  u16*   xent  = (u16*)take(NKf * 2);
  u16*   hA    = (u16*)take(NKf * 2);
  u16*   hB    = (u16*)take(NKf * 2);
  float* Sx    = (float*)take(NKf * 4);
  float* Ss    = (float*)take(NKf * 4);
  u16*   Ssb   = (u16*)take(NKf * 2);
  float* semb  = (float*)take((size_t)BB * KK * 4);
  float* cstu  = (float*)take(KK * 4);
  float* cexer = (float*)take(KK * 4);
  u16*   Bsw   = (u16*)take((size_t)3 * 49152 * 2);
  float* bsum  = (float*)take((size_t)3 * KK * 4);
  u32*   degI  = (u32*)take((size_t)3 * NN * 4);
  float* rsdO  = (float*)take((size_t)3 * NN * 4);
  float* rsdI  = (float*)take((size_t)3 * NN * 4);
  u32*   rp    = (u32*)take((size_t)3 * (NN + 1) * 4);
  uint2* edata = (uint2*)take((size_t)3 * EE * 8);
  u32*   slabO = (u32*)take((size_t)3 * NB * NP * 4);
  u32*   slabI = (u32*)take((size_t)3 * NB * NP * 4);
  (void)ws_size; (void)in_sizes; (void)n_in; (void)out_size;

  k_hist<<<dim3(NB, 3), 256, 0, stream>>>(s0, dd0, s1, dd1, s2, dd2, slabO, slabI);
  k_reduce<<<dim3((NP + 255) / 256, 3), 256, 0, stream>>>(slabO, slabI, degI, rsdO, rsdI);
  k_exscan2<<<3, 1024, 0, stream>>>(degI, rp);
  k_scatter2<<<dim3(NB, 3), 256, 0, stream>>>(s0, dd0, s1, dd1, s2, dd2, slabI, rp,
                                              rsdO, rsdI, edata);
  k_prep<<<1106, 256, 0, stream>>>(entity, xent, gcnW, Bsw, gcnB, bsum);

  const u16* xs[3] = {xent, hA, hB};
  u16* outs[3]     = {hA, hB, hA};
  const int modes[3] = {1, 2, 4 | 8};
  for (int l = 0; l < 3; ++l)
    k_layer<<<NN / 32, 512, 0, stream>>>(xs[l], rp, edata, Bsw + (size_t)l * 49152,
                                         bsum + (size_t)l * KK, outs[l], entity,
                                         Sx, Ss, Ssb, modes[l]);

  k_post<<<544, 256, 0, stream>>>(Ssb, history, hlen, semb, Sx, Wstu, Wexer, cstu, cexer);
  k_final<<<BB * 64 / 256, 256, 0, stream>>>(Sx, semb, cstu, cexer, Wstu, Wexer, W3, disc,
                                             exer_id, kn, bstu, bexer, b3, (float*)d_out);
}

// Round 6
// 191.959 us; speedup vs baseline: 3.2191x; 1.2166x over previous
//
#include <hip/hip_runtime.h>

#define NN 16512      // N = K + EXER nodes
#define KK 128        // feature dim
#define K3 384        // 3 graphs concatenated along K
#define EE 262144     // edges per graph
#define BB 2048       // batch
#define HH 64         // history length
#define NKf ((size_t)NN * KK)
#define NB 64         // hist blocks per graph
#define EPB (EE / NB) // 4096 edges per block
#define NP (NN / 2)   // 8256 packed u16-pair counters
#define RPB 16        // rows per k_layer block
#define CAP 512       // staged edges per graph per block (mean ~254)

typedef unsigned int u32;
typedef unsigned short u16;
typedef short bf16x8 __attribute__((ext_vector_type(8)));
typedef float f32x4 __attribute__((ext_vector_type(4)));

__device__ __forceinline__ float sgm(float x) { return 1.0f / (1.0f + __expf(-x)); }

__device__ __forceinline__ u16 f2bf(float f) {          // round-to-nearest-even
  u32 u = __float_as_uint(f);
  u32 r = u + 0x7fffu + ((u >> 16) & 1u);
  return (u16)(r >> 16);
}
__device__ __forceinline__ float bflo(u32 p) { return __uint_as_float(p << 16); }
__device__ __forceinline__ float bfhi(u32 p) { return __uint_as_float(p & 0xffff0000u); }

// ---------------- graph preprocessing (atomic-free counting sort) ----------------

__global__ __launch_bounds__(256) void k_hist(
    const int* __restrict__ s0, const int* __restrict__ d0,
    const int* __restrict__ s1, const int* __restrict__ d1,
    const int* __restrict__ s2, const int* __restrict__ d2,
    u32* __restrict__ slabO, u32* __restrict__ slabI) {
  int g = blockIdx.y, b = blockIdx.x;
  const int* src = g == 0 ? s0 : (g == 1 ? s1 : s2);
  const int* dst = g == 0 ? d0 : (g == 1 ? d1 : d2);
  __shared__ u32 hO[NP], hI[NP];
  for (int i = threadIdx.x; i < NP; i += 256) { hO[i] = 0; hI[i] = 0; }
  __syncthreads();
  int base = b * EPB;
  for (int i = threadIdx.x; i < EPB; i += 256) {
    int s = src[base + i], d = dst[base + i];
    atomicAdd(&hO[s >> 1], 1u << ((s & 1) * 16));
    atomicAdd(&hI[d >> 1], 1u << ((d & 1) * 16));
  }
  __syncthreads();
  u32* oO = slabO + ((size_t)g * NB + b) * NP;
  u32* oI = slabI + ((size_t)g * NB + b) * NP;
  for (int i = threadIdx.x; i < NP; i += 256) { oO[i] = hO[i]; oI[i] = hI[i]; }
}

__global__ void k_reduce(u32* __restrict__ slabO, u32* __restrict__ slabI,
                         u32* __restrict__ degI, float* __restrict__ rsdO,
                         float* __restrict__ rsdI) {
  int g = blockIdx.y;
  int t = blockIdx.x * 256 + threadIdx.x;
  if (t >= NP) return;
  u32* sO = slabO + (size_t)g * NB * NP + t;
  u32* sI = slabI + (size_t)g * NB * NP + t;
  u32 sumO = 0, pre = 0;
  #pragma unroll 8
  for (int b = 0; b < NB; ++b) sumO += sO[(size_t)b * NP];
  #pragma unroll 8
  for (int b = 0; b < NB; ++b) {
    u32 v = sI[(size_t)b * NP];
    sI[(size_t)b * NP] = pre;          // packed u16 exclusive prefix
    pre += v;
  }
  u32 dOl = sumO & 0xffffu, dOh = sumO >> 16;
  u32 dIl = pre & 0xffffu,  dIh = pre >> 16;
  *(uint2*)(degI + (size_t)g * NN + 2 * t) = make_uint2(dIl, dIh);
  *(float2*)(rsdO + (size_t)g * NN + 2 * t) =
      make_float2(rsqrtf((float)(dOl ? dOl : 1u)), rsqrtf((float)(dOh ? dOh : 1u)));
  *(float2*)(rsdI + (size_t)g * NN + 2 * t) =
      make_float2(rsqrtf((float)(dIl ? dIl : 1u)), rsqrtf((float)(dIh ? dIh : 1u)));
}

__global__ __launch_bounds__(1024) void k_exscan2(const u32* __restrict__ degI,
                                                  u32* __restrict__ rps) {
  int g = blockIdx.x;
  const u32* deg = degI + (size_t)g * NN;
  u32* rp = rps + (size_t)g * (NN + 1);
  int t = threadIdx.x;
  int i0 = t * 17, i1 = i0 + 17 < NN ? i0 + 17 : NN;
  u32 s = 0;
  for (int i = i0; i < i1; ++i) s += deg[i];
  u32 x = s;
  int lane = t & 63, wid = t >> 6;
  #pragma unroll
  for (int off = 1; off < 64; off <<= 1) {
    u32 y = __shfl_up(x, off);
    if (lane >= off) x += y;
  }
  __shared__ u32 wsums[16];
  if (lane == 63) wsums[wid] = x;
  __syncthreads();
  if (t == 0) {
    u32 run = 0;
    #pragma unroll
    for (int i = 0; i < 16; ++i) { u32 tmp = wsums[i]; wsums[i] = run; run += tmp; }
  }
  __syncthreads();
  u32 run = wsums[wid] + x - s;
  for (int i = i0; i < i1; ++i) { rp[i] = run; run += deg[i]; }
  if (t == 0) rp[NN] = EE;
}

// edata[idx] = { src, norm(f32) } -> single 8B store per edge
__global__ __launch_bounds__(256) void k_scatter2(
    const int* __restrict__ s0, const int* __restrict__ d0,
    const int* __restrict__ s1, const int* __restrict__ d1,
    const int* __restrict__ s2, const int* __restrict__ d2,
    const u32* __restrict__ slabI, const u32* __restrict__ rps,
    const float* __restrict__ rsdO, const float* __restrict__ rsdI,
    uint2* __restrict__ edatas) {
  int g = blockIdx.y, b = blockIdx.x;
  const int* src = g == 0 ? s0 : (g == 1 ? s1 : s2);
  const int* dst = g == 0 ? d0 : (g == 1 ? d1 : d2);
  const u32* rp = rps + (size_t)g * (NN + 1);
  const u32* pre = slabI + ((size_t)g * NB + b) * NP;
  const float* rO = rsdO + (size_t)g * NN;
  const float* rI = rsdI + (size_t)g * NN;
  uint2* ed = edatas + (size_t)g * EE;
  __shared__ u32 cur[NN];
  for (int i = threadIdx.x; i < NP; i += 256) {
    u32 p = pre[i];
    cur[2 * i]     = rp[2 * i] + (p & 0xffffu);
    cur[2 * i + 1] = rp[2 * i + 1] + (p >> 16);
  }
  __syncthreads();
  int base = b * EPB;
  for (int i = threadIdx.x; i < EPB; i += 256) {
    int s = src[base + i], d = dst[base + i];
    u32 idx = atomicAdd(&cur[d], 1u);
    ed[idx] = make_uint2((u32)s, __float_as_uint(rO[s] * rI[d]));
  }
}

// ---------------- fused prep: entity->bf16 | W pre-swizzle | bias sums ----------------
// Bsw[((l*96 + nb*12 + ks)*64 + lane)*8 + j] = bf16( W[l, g, kin, kout] )
//   k = ks*32 + (lane>>4)*8 + j ; g = k>>7 ; kin = k&127 ; kout = nb*16 + (lane&15)

__global__ void k_prep(const float* __restrict__ entity, u16* __restrict__ xent,
                       const float* __restrict__ W, u16* __restrict__ Bsw,
                       const float* __restrict__ b, float* __restrict__ bsum) {
  int bid = blockIdx.x;
  if (bid < 1032) {                       // cvt: NN*KK/8 = 264192 items
    int t = bid * 256 + threadIdx.x;
    if (t >= NN * KK / 8) return;
    const float4* p = (const float4*)entity + (size_t)t * 2;
    float4 v0 = p[0], v1 = p[1];
    bf16x8 o;
    o[0] = (short)f2bf(v0.x); o[1] = (short)f2bf(v0.y);
    o[2] = (short)f2bf(v0.z); o[3] = (short)f2bf(v0.w);
    o[4] = (short)f2bf(v1.x); o[5] = (short)f2bf(v1.y);
    o[6] = (short)f2bf(v1.z); o[7] = (short)f2bf(v1.w);
    *(bf16x8*)(xent + (size_t)t * 8) = o;
  } else if (bid < 1104) {                // prepB: 18432 items
    int t = (bid - 1032) * 256 + threadIdx.x;
    if (t >= 3 * 8 * 12 * 64) return;
    int lane = t & 63;
    int ks = (t >> 6) % 12;
    int nb = ((t >> 6) / 12) % 8;
    int l  = (t >> 6) / 96;
    int kout = nb * 16 + (lane & 15);
    int kb = ks * 32 + (lane >> 4) * 8;
    bf16x8 v;
    #pragma unroll
    for (int j = 0; j < 8; ++j) {
      int k = kb + j; int g = k >> 7; int kin = k & 127;
      v[j] = (short)f2bf(W[(((size_t)l * 3 + g) * KK + kin) * KK + kout]);
    }
    *(bf16x8*)(Bsw + (size_t)t * 8) = v;
  } else {                                // bias sums: 384 items
    int t = (bid - 1104) * 256 + threadIdx.x;
    if (t >= 3 * KK) return;
    int l = t >> 7, c = t & 127;
    bsum[l * KK + c] = b[(l * 3 + 0) * KK + c] + b[(l * 3 + 1) * KK + c] + b[(l * 3 + 2) * KK + c];
  }
}

// ---------------- fused layer: SpMM (3 graphs -> LDS) + MFMA GEMM + epilogue ----------
// Block owns 16 rows; 8 waves; 48 SpMM tasks, quad-edge layout; edge meta staged in LDS.
// mode: 1 = Sx = entity + v ; else Sx += v
//       2 = Ss = v ; 4 = Ssb = bf16(Ss + v) ; 8 = skip h write

#define GATHER_LOOP(MP)                                            \
  for (; e + 4 <= cnt; e += 4) {                                   \
    uint2 m = MP[e + slot];                                        \
    float n = __uint_as_float(m.y);                                \
    uint4 p = *(const uint4*)(x + (size_t)m.x * KK + cg * 8);      \
    acc[0] += bflo(p.x) * n; acc[1] += bfhi(p.x) * n;              \
    acc[2] += bflo(p.y) * n; acc[3] += bfhi(p.y) * n;              \
    acc[4] += bflo(p.z) * n; acc[5] += bfhi(p.z) * n;              \
    acc[6] += bflo(p.w) * n; acc[7] += bfhi(p.w) * n;              \
  }                                                                \
  if (e + slot < cnt) {                                            \
    uint2 m = MP[e + slot];                                        \
    float n = __uint_as_float(m.y);                                \
    uint4 p = *(const uint4*)(x + (size_t)m.x * KK + cg * 8);      \
    acc[0] += bflo(p.x) * n; acc[1] += bfhi(p.x) * n;              \
    acc[2] += bflo(p.y) * n; acc[3] += bfhi(p.y) * n;              \
    acc[4] += bflo(p.z) * n; acc[5] += bfhi(p.z) * n;              \
    acc[6] += bflo(p.w) * n; acc[7] += bfhi(p.w) * n;              \
  }

__global__ __launch_bounds__(512) void k_layer(
    const u16* __restrict__ x, const u32* __restrict__ rps,
    const uint2* __restrict__ edatas, const u16* __restrict__ Bsw,
    const float* __restrict__ bsum, u16* __restrict__ hout,
    const float* __restrict__ entity, float* __restrict__ Sx,
    float* __restrict__ Ss, u16* __restrict__ Ssb, int mode)
{
  __shared__ u16 At[RPB][392];            // 12.25 KB; row stride 784B -> 2-way (free)
  __shared__ uint2 meta[3][CAP];          // 12 KB staged edge metadata
  __shared__ u32 rpl[3][RPB + 1];         // row pointers
  const int tid = threadIdx.x;
  const int wv = tid >> 6, lane = tid & 63;
  const int m0 = blockIdx.x * RPB;
  const int slot = lane >> 4, cg = lane & 15;

  if (tid < 3 * (RPB + 1))
    rpl[tid / (RPB + 1)][tid % (RPB + 1)] =
        rps[(size_t)(tid / (RPB + 1)) * (NN + 1) + m0 + tid % (RPB + 1)];
  __syncthreads();

  // ---- stage edge metadata (contiguous CSR slices) ----
  #pragma unroll
  for (int g = 0; g < 3; ++g) {
    u32 b0 = rpl[g][0];
    u32 cnt = rpl[g][RPB] - b0; if (cnt > CAP) cnt = CAP;
    const uint2* ed = edatas + (size_t)g * EE + b0;
    for (u32 i = tid; i < cnt; i += 512) meta[g][i] = ed[i];
  }
  __syncthreads();

  // ---- SpMM phase: 48 tasks ----
  for (int t = wv; t < 48; t += 8) {
    int g = t >> 4, r = t & 15;
    u32 beg = rpl[g][r], end = rpl[g][r + 1];
    u32 cnt = end - beg, e = 0;
    float acc[8] = {0.f, 0.f, 0.f, 0.f, 0.f, 0.f, 0.f, 0.f};
    if (end - rpl[g][0] <= CAP) {
      const uint2* mp = &meta[g][beg - rpl[g][0]];
      GATHER_LOOP(mp)
    } else {                              // overflow fallback (rare)
      const uint2* mp = edatas + (size_t)g * EE + beg;
      GATHER_LOOP(mp)
    }
    #pragma unroll
    for (int i = 0; i < 8; ++i) {
      acc[i] += __shfl_xor(acc[i], 16);
      acc[i] += __shfl_xor(acc[i], 32);
    }
    if (slot == 0) {
      u32 o0 = ((u32)f2bf(acc[1]) << 16) | (u32)f2bf(acc[0]);
      u32 o1 = ((u32)f2bf(acc[3]) << 16) | (u32)f2bf(acc[2]);
      u32 o2 = ((u32)f2bf(acc[5]) << 16) | (u32)f2bf(acc[4]);
      u32 o3 = ((u32)f2bf(acc[7]) << 16) | (u32)f2bf(acc[6]);
      *(uint4*)(&At[r][g * KK + cg * 8]) = make_uint4(o0, o1, o2, o3);
    }
  }
  __syncthreads();

  // ---- MFMA phase: 16x128 = At(16x384) @ B(384x128); wave wv -> cols wv*16.. ----
  const int lr = lane & 15, lk = lane >> 4;
  f32x4 acc2 = {0.f, 0.f, 0.f, 0.f};
  const u16* aB = Bsw + (size_t)wv * 6144 + (size_t)lane * 8;
  #pragma unroll
  for (int ks = 0; ks < 12; ++ks) {
    bf16x8 a = *(const bf16x8*)(&At[lr][ks * 32 + lk * 8]);
    bf16x8 b = *(const bf16x8*)(aB + ks * 512);
    acc2 = __builtin_amdgcn_mfma_f32_16x16x32_bf16(a, b, acc2, 0, 0, 0);
  }

  int col = wv * 16 + lr;
  float bv = bsum[col];
  int rowb = m0 + lk * 4;
  #pragma unroll
  for (int r = 0; r < 4; ++r) {
    size_t idx = (size_t)(rowb + r) * KK + col;
    float v = acc2[r] + bv;
    if (!(mode & 8)) hout[idx] = f2bf(v);
    float sx = (mode & 1) ? (entity[idx] + v) : (Sx[idx] + v);
    Sx[idx] = sx;
    if (mode & 2) Ss[idx] = v;
    else if (mode & 4) Ssb[idx] = f2bf(Ss[idx] + v);
  }
}

// ---------------- fused post: history mean (quad rows) + concept projections ----------

__global__ __launch_bounds__(256) void k_post(
    const u16* __restrict__ Ssb, const int* __restrict__ hist, const int* __restrict__ hlen,
    float* __restrict__ semb, const float* __restrict__ Sx,
    const float* __restrict__ Wstu, const float* __restrict__ Wexer,
    float* __restrict__ cstu, float* __restrict__ cexer)
{
  int wv = threadIdx.x >> 6, lane = threadIdx.x & 63;
  if (blockIdx.x < 512) {                 // stuemb: 2048 items
    int item = blockIdx.x * 4 + wv;
    int slot = lane >> 4, cg = lane & 15;
    int len = hlen[item];
    const int* hrow = hist + item * HH;
    float acc[8] = {0.f, 0.f, 0.f, 0.f, 0.f, 0.f, 0.f, 0.f};
    int h = 0;
    for (; h + 4 <= len; h += 4) {
      int id = hrow[h + slot];
      uint4 p = *(const uint4*)(Ssb + (size_t)(KK + id) * KK + cg * 8);
      acc[0] += bflo(p.x); acc[1] += bfhi(p.x);
      acc[2] += bflo(p.y); acc[3] += bfhi(p.y);
      acc[4] += bflo(p.z); acc[5] += bfhi(p.z);
      acc[6] += bflo(p.w); acc[7] += bfhi(p.w);
    }
    if (h + slot < len) {
      int id = hrow[h + slot];
      uint4 p = *(const uint4*)(Ssb + (size_t)(KK + id) * KK + cg * 8);
      acc[0] += bflo(p.x); acc[1] += bfhi(p.x);
      acc[2] += bflo(p.y); acc[3] += bfhi(p.y);
      acc[4] += bflo(p.z); acc[5] += bfhi(p.z);
      acc[6] += bflo(p.w); acc[7] += bfhi(p.w);
    }
    #pragma unroll
    for (int i = 0; i < 8; ++i) {
      acc[i] += __shfl_xor(acc[i], 16);
      acc[i] += __shfl_xor(acc[i], 32);
    }
    if (slot == 0) {
      float sc = 0.5f / (float)len;
      float4 o0 = make_float4(acc[0] * sc, acc[1] * sc, acc[2] * sc, acc[3] * sc);
      float4 o1 = make_float4(acc[4] * sc, acc[5] * sc, acc[6] * sc, acc[7] * sc);
      *(float4*)(semb + (size_t)item * KK + cg * 8) = o0;
      *(float4*)(semb + (size_t)item * KK + cg * 8 + 4) = o1;
    }
  } else {                                // cproj: 128 concept rows
    int w = (blockIdx.x - 512) * 4 + wv;
    float2 c = *(const float2*)(Sx + (size_t)w * KK + lane * 2);
    c.x *= 0.25f; c.y *= 0.25f;
    float2 ws = *(const float2*)(Wstu + KK + lane * 2);
    float2 we = *(const float2*)(Wexer + KK + lane * 2);
    float ps = c.x * ws.x + c.y * ws.y;
    float pe = c.x * we.x + c.y * we.y;
    #pragma unroll
    for (int off = 32; off; off >>= 1) { ps += __shfl_xor(ps, off); pe += __shfl_xor(pe, off); }
    if (lane == 0) { cstu[w] = ps; cexer[w] = pe; }
  }
}

__global__ void k_final(const float* __restrict__ Sx, const float* __restrict__ semb,
                        const float* __restrict__ cstu, const float* __restrict__ cexer,
                        const float* __restrict__ Wstu, const float* __restrict__ Wexer,
                        const float* __restrict__ W3, const float* __restrict__ disc,
                        const int* __restrict__ exid, const float* __restrict__ kn,
                        const float* __restrict__ bstu, const float* __restrict__ bexer,
                        const float* __restrict__ b3, float* __restrict__ out) {
  int w = (blockIdx.x * 256 + threadIdx.x) >> 6;   // batch index
  int lane = threadIdx.x & 63;
  if (w >= BB) return;
  int eid = exid[w];
  float2 se = *(const float2*)(Sx + ((size_t)(KK + eid)) * KK + lane * 2);
  se.x *= 0.25f; se.y *= 0.25f;                    // exer_emb
  float2 sm = *(const float2*)(semb + (size_t)w * KK + lane * 2);
  float2 ws = *(const float2*)(Wstu + lane * 2);
  float2 we = *(const float2*)(Wexer + lane * 2);
  float ps = sm.x * ws.x + sm.y * ws.y;
  float pe = se.x * we.x + se.y * we.y;
  #pragma unroll
  for (int off = 32; off; off >>= 1) { ps += __shfl_xor(ps, off); pe += __shfl_xor(pe, off); }
  float s_stu = ps + bstu[0];
  float s_exer = pe + bexer[0];
  float ed = 10.f * sgm(disc[eid]);
  float2 cs = *(const float2*)(cstu + lane * 2);
  float2 ce = *(const float2*)(cexer + lane * 2);
  float2 knv = *(const float2*)(kn + (size_t)w * KK + lane * 2);
  float x0 = ed * (sgm(s_stu + cs.x) - sgm(s_exer + ce.x)) * knv.x;
  float x1 = ed * (sgm(s_stu + cs.y) - sgm(s_exer + ce.y)) * knv.y;
  float2 w3v = *(const float2*)(W3 + lane * 2);
  float px = x0 * w3v.x + x1 * w3v.y;
  #pragma unroll
  for (int off = 32; off; off >>= 1) px += __shfl_xor(px, off);
  if (lane == 0) out[w] = sgm(px + b3[0]);
}

// ---------------- host ----------------

extern "C" void kernel_launch(void* const* d_in, const int* in_sizes, int n_in,
                              void* d_out, int out_size, void* d_ws, size_t ws_size,
                              hipStream_t stream)
{
  const float* entity = (const float*)d_in[0];
  const float* gcnW   = (const float*)d_in[1];
  const float* gcnB   = (const float*)d_in[2];
  const float* disc   = (const float*)d_in[3];
  const float* Wstu   = (const float*)d_in[4];
  const float* bstu   = (const float*)d_in[5];
  const float* Wexer  = (const float*)d_in[6];
  const float* bexer  = (const float*)d_in[7];
  const float* W3     = (const float*)d_in[8];
  const float* b3     = (const float*)d_in[9];
  const float* kn     = (const float*)d_in[10];
  const int* exer_id  = (const int*)d_in[12];
  const int* history  = (const int*)d_in[14];
  const int* hlen     = (const int*)d_in[15];
  const int* s0 = (const int*)d_in[16], *dd0 = (const int*)d_in[17];
  const int* s1 = (const int*)d_in[18], *dd1 = (const int*)d_in[19];
  const int* s2 = (const int*)d_in[20], *dd2 = (const int*)d_in[21];

  char* ws = (char*)d_ws;
  size_t off = 0;
  auto take = [&](size_t bytes) -> char* {
    char* p = ws + off;
    off = (off + bytes + 255) & ~(size_t)255;
    return p;
  };
  u16*   xent  = (u16*)take(NKf * 2);
  u16*   hA    = (u16*)take(NKf * 2);
  u16*   hB    = (u16*)take(NKf * 2);
  float* Sx    = (float*)take(NKf * 4);
  float* Ss    = (float*)take(NKf * 4);
  u16*   Ssb   = (u16*)take(NKf * 2);
  float* semb  = (float*)take((size_t)BB * KK * 4);
  float* cstu  = (float*)take(KK * 4);
  float* cexer = (float*)take(KK * 4);
  u16*   Bsw   = (u16*)take((size_t)3 * 49152 * 2);
  float* bsum  = (float*)take((size_t)3 * KK * 4);
  u32*   degI  = (u32*)take((size_t)3 * NN * 4);
  float* rsdO  = (float*)take((size_t)3 * NN * 4);
  float* rsdI  = (float*)take((size_t)3 * NN * 4);
  u32*   rp    = (u32*)take((size_t)3 * (NN + 1) * 4);
  uint2* edata = (uint2*)take((size_t)3 * EE * 8);
  u32*   slabO = (u32*)take((size_t)3 * NB * NP * 4);
  u32*   slabI = (u32*)take((size_t)3 * NB * NP * 4);
  (void)ws_size; (void)in_sizes; (void)n_in; (void)out_size;

  k_hist<<<dim3(NB, 3), 256, 0, stream>>>(s0, dd0, s1, dd1, s2, dd2, slabO, slabI);
  k_reduce<<<dim3((NP + 255) / 256, 3), 256, 0, stream>>>(slabO, slabI, degI, rsdO, rsdI);
  k_exscan2<<<3, 1024, 0, stream>>>(degI, rp);
  k_scatter2<<<dim3(NB, 3), 256, 0, stream>>>(s0, dd0, s1, dd1, s2, dd2, slabI, rp,
                                              rsdO, rsdI, edata);
  k_prep<<<1106, 256, 0, stream>>>(entity, xent, gcnW, Bsw, gcnB, bsum);

  const u16* xs[3] = {xent, hA, hB};
  u16* outs[3]     = {hA, hB, hA};
  const int modes[3] = {1, 2, 4 | 8};
  for (int l = 0; l < 3; ++l)
    k_layer<<<NN / RPB, 512, 0, stream>>>(xs[l], rp, edata, Bsw + (size_t)l * 49152,
                                          bsum + (size_t)l * KK, outs[l], entity,
                                          Sx, Ss, Ssb, modes[l]);

  k_post<<<544, 256, 0, stream>>>(Ssb, history, hlen, semb, Sx, Wstu, Wexer, cstu, cexer);
  k_final<<<BB * 64 / 256, 256, 0, stream>>>(Sx, semb, cstu, cexer, Wstu, Wexer, W3, disc,
                                             exer_id, kn, bstu, bexer, b3, (float*)d_out);
}

// Round 7
// 183.635 us; speedup vs baseline: 3.3650x; 1.0453x over previous
//
#include <hip/hip_runtime.h>

#define NN 16512      // N = K + EXER nodes
#define KK 128        // feature dim
#define K3 384        // 3 graphs concatenated along K
#define EE 262144     // edges per graph
#define BB 2048       // batch
#define HH 64         // history length
#define NKf ((size_t)NN * KK)
#define NB 64         // hist blocks per graph
#define EPB (EE / NB) // 4096 edges per block
#define NP (NN / 2)   // 8256 packed u16-pair counters
#define RPB 16        // rows per k_layer block
#define CAP 512       // staged edges per graph per block (mean ~254)

typedef unsigned int u32;
typedef unsigned short u16;
typedef short bf16x8 __attribute__((ext_vector_type(8)));
typedef float f32x4 __attribute__((ext_vector_type(4)));

__device__ __forceinline__ float sgm(float x) { return 1.0f / (1.0f + __expf(-x)); }

__device__ __forceinline__ u16 f2bf(float f) {          // round-to-nearest-even
  u32 u = __float_as_uint(f);
  u32 r = u + 0x7fffu + ((u >> 16) & 1u);
  return (u16)(r >> 16);
}
__device__ __forceinline__ float bflo(u32 p) { return __uint_as_float(p << 16); }
__device__ __forceinline__ float bfhi(u32 p) { return __uint_as_float(p & 0xffff0000u); }

// ---------------- graph preprocessing (atomic-free counting sort) ----------------

__global__ __launch_bounds__(256) void k_hist(
    const int* __restrict__ s0, const int* __restrict__ d0,
    const int* __restrict__ s1, const int* __restrict__ d1,
    const int* __restrict__ s2, const int* __restrict__ d2,
    u32* __restrict__ slabO, u32* __restrict__ slabI) {
  int g = blockIdx.y, b = blockIdx.x;
  const int* src = g == 0 ? s0 : (g == 1 ? s1 : s2);
  const int* dst = g == 0 ? d0 : (g == 1 ? d1 : d2);
  __shared__ u32 hO[NP], hI[NP];
  for (int i = threadIdx.x; i < NP; i += 256) { hO[i] = 0; hI[i] = 0; }
  __syncthreads();
  int base = b * EPB;
  for (int i = threadIdx.x; i < EPB; i += 256) {
    int s = src[base + i], d = dst[base + i];
    atomicAdd(&hO[s >> 1], 1u << ((s & 1) * 16));
    atomicAdd(&hI[d >> 1], 1u << ((d & 1) * 16));
  }
  __syncthreads();
  u32* oO = slabO + ((size_t)g * NB + b) * NP;
  u32* oI = slabI + ((size_t)g * NB + b) * NP;
  for (int i = threadIdx.x; i < NP; i += 256) { oO[i] = hO[i]; oI[i] = hI[i]; }
}

__global__ void k_reduce(u32* __restrict__ slabO, u32* __restrict__ slabI,
                         u32* __restrict__ degI, float* __restrict__ rsdO,
                         float* __restrict__ rsdI) {
  int g = blockIdx.y;
  int t = blockIdx.x * 256 + threadIdx.x;
  if (t >= NP) return;
  u32* sO = slabO + (size_t)g * NB * NP + t;
  u32* sI = slabI + (size_t)g * NB * NP + t;
  u32 sumO = 0, pre = 0;
  #pragma unroll 8
  for (int b = 0; b < NB; ++b) sumO += sO[(size_t)b * NP];
  #pragma unroll 8
  for (int b = 0; b < NB; ++b) {
    u32 v = sI[(size_t)b * NP];
    sI[(size_t)b * NP] = pre;          // packed u16 exclusive prefix
    pre += v;
  }
  u32 dOl = sumO & 0xffffu, dOh = sumO >> 16;
  u32 dIl = pre & 0xffffu,  dIh = pre >> 16;
  *(uint2*)(degI + (size_t)g * NN + 2 * t) = make_uint2(dIl, dIh);
  *(float2*)(rsdO + (size_t)g * NN + 2 * t) =
      make_float2(rsqrtf((float)(dOl ? dOl : 1u)), rsqrtf((float)(dOh ? dOh : 1u)));
  *(float2*)(rsdI + (size_t)g * NN + 2 * t) =
      make_float2(rsqrtf((float)(dIl ? dIl : 1u)), rsqrtf((float)(dIh ? dIh : 1u)));
}

__global__ __launch_bounds__(1024) void k_exscan2(const u32* __restrict__ degI,
                                                  u32* __restrict__ rps) {
  int g = blockIdx.x;
  const u32* deg = degI + (size_t)g * NN;
  u32* rp = rps + (size_t)g * (NN + 1);
  int t = threadIdx.x;
  int i0 = t * 17, i1 = i0 + 17 < NN ? i0 + 17 : NN;
  u32 s = 0;
  for (int i = i0; i < i1; ++i) s += deg[i];
  u32 x = s;
  int lane = t & 63, wid = t >> 6;
  #pragma unroll
  for (int off = 1; off < 64; off <<= 1) {
    u32 y = __shfl_up(x, off);
    if (lane >= off) x += y;
  }
  __shared__ u32 wsums[16];
  if (lane == 63) wsums[wid] = x;
  __syncthreads();
  if (t == 0) {
    u32 run = 0;
    #pragma unroll
    for (int i = 0; i < 16; ++i) { u32 tmp = wsums[i]; wsums[i] = run; run += tmp; }
  }
  __syncthreads();
  u32 run = wsums[wid] + x - s;
  for (int i = i0; i < i1; ++i) { rp[i] = run; run += deg[i]; }
  if (t == 0) rp[NN] = EE;
}

// edata[idx] = { src, norm(f32) } -> single 8B store per edge
__global__ __launch_bounds__(256) void k_scatter2(
    const int* __restrict__ s0, const int* __restrict__ d0,
    const int* __restrict__ s1, const int* __restrict__ d1,
    const int* __restrict__ s2, const int* __restrict__ d2,
    const u32* __restrict__ slabI, const u32* __restrict__ rps,
    const float* __restrict__ rsdO, const float* __restrict__ rsdI,
    uint2* __restrict__ edatas) {
  int g = blockIdx.y, b = blockIdx.x;
  const int* src = g == 0 ? s0 : (g == 1 ? s1 : s2);
  const int* dst = g == 0 ? d0 : (g == 1 ? d1 : d2);
  const u32* rp = rps + (size_t)g * (NN + 1);
  const u32* pre = slabI + ((size_t)g * NB + b) * NP;
  const float* rO = rsdO + (size_t)g * NN;
  const float* rI = rsdI + (size_t)g * NN;
  uint2* ed = edatas + (size_t)g * EE;
  __shared__ u32 cur[NN];
  for (int i = threadIdx.x; i < NP; i += 256) {
    u32 p = pre[i];
    cur[2 * i]     = rp[2 * i] + (p & 0xffffu);
    cur[2 * i + 1] = rp[2 * i + 1] + (p >> 16);
  }
  __syncthreads();
  int base = b * EPB;
  for (int i = threadIdx.x; i < EPB; i += 256) {
    int s = src[base + i], d = dst[base + i];
    u32 idx = atomicAdd(&cur[d], 1u);
    ed[idx] = make_uint2((u32)s, __float_as_uint(rO[s] * rI[d]));
  }
}

// ---------------- fused prep: entity->bf16 | W pre-swizzle | bias sums ----------------
// Bsw[((l*96 + nb*12 + ks)*64 + lane)*8 + j] = bf16( W[l, g, kin, kout] )
//   k = ks*32 + (lane>>4)*8 + j ; g = k>>7 ; kin = k&127 ; kout = nb*16 + (lane&15)

__global__ void k_prep(const float* __restrict__ entity, u16* __restrict__ xent,
                       const float* __restrict__ W, u16* __restrict__ Bsw,
                       const float* __restrict__ b, float* __restrict__ bsum) {
  int bid = blockIdx.x;
  if (bid < 1032) {                       // cvt: NN*KK/8 = 264192 items
    int t = bid * 256 + threadIdx.x;
    if (t >= NN * KK / 8) return;
    const float4* p = (const float4*)entity + (size_t)t * 2;
    float4 v0 = p[0], v1 = p[1];
    bf16x8 o;
    o[0] = (short)f2bf(v0.x); o[1] = (short)f2bf(v0.y);
    o[2] = (short)f2bf(v0.z); o[3] = (short)f2bf(v0.w);
    o[4] = (short)f2bf(v1.x); o[5] = (short)f2bf(v1.y);
    o[6] = (short)f2bf(v1.z); o[7] = (short)f2bf(v1.w);
    *(bf16x8*)(xent + (size_t)t * 8) = o;
  } else if (bid < 1104) {                // prepB: 18432 items
    int t = (bid - 1032) * 256 + threadIdx.x;
    if (t >= 3 * 8 * 12 * 64) return;
    int lane = t & 63;
    int ks = (t >> 6) % 12;
    int nb = ((t >> 6) / 12) % 8;
    int l  = (t >> 6) / 96;
    int kout = nb * 16 + (lane & 15);
    int kb = ks * 32 + (lane >> 4) * 8;
    bf16x8 v;
    #pragma unroll
    for (int j = 0; j < 8; ++j) {
      int k = kb + j; int g = k >> 7; int kin = k & 127;
      v[j] = (short)f2bf(W[(((size_t)l * 3 + g) * KK + kin) * KK + kout]);
    }
    *(bf16x8*)(Bsw + (size_t)t * 8) = v;
  } else {                                // bias sums: 384 items
    int t = (bid - 1104) * 256 + threadIdx.x;
    if (t >= 3 * KK) return;
    int l = t >> 7, c = t & 127;
    bsum[l * KK + c] = b[(l * 3 + 0) * KK + c] + b[(l * 3 + 1) * KK + c] + b[(l * 3 + 2) * KK + c];
  }
}

// ---------------- fused layer: SpMM (3 graphs -> LDS) + MFMA GEMM + epilogue ----------
// Block owns 16 rows; 8 waves; 48 SpMM tasks, quad-edge layout; edge meta staged in LDS.
// Gather unrolled 4x (16 edges/iter): 4 independent wave-wide loads in flight.
// mode: 1 = Sx = entity + v ; else Sx += v
//       2 = Ss = v ; 4 = Ssb = bf16(Ss + v) ; 8 = skip h write

#define ACC8(P, N)                                                 \
  acc[0] += bflo(P.x) * N; acc[1] += bfhi(P.x) * N;                \
  acc[2] += bflo(P.y) * N; acc[3] += bfhi(P.y) * N;                \
  acc[4] += bflo(P.z) * N; acc[5] += bfhi(P.z) * N;                \
  acc[6] += bflo(P.w) * N; acc[7] += bfhi(P.w) * N;

#define GATHER_LOOP(MP)                                            \
  for (; e + 16 <= cnt; e += 16) {                                 \
    uint2 ma = MP[e + slot];                                       \
    uint2 mb = MP[e + 4 + slot];                                   \
    uint2 mc = MP[e + 8 + slot];                                   \
    uint2 md = MP[e + 12 + slot];                                  \
    uint4 pa = *(const uint4*)(x + (size_t)ma.x * KK + cg * 8);    \
    uint4 pb = *(const uint4*)(x + (size_t)mb.x * KK + cg * 8);    \
    uint4 pc = *(const uint4*)(x + (size_t)mc.x * KK + cg * 8);    \
    uint4 pd = *(const uint4*)(x + (size_t)md.x * KK + cg * 8);    \
    float na = __uint_as_float(ma.y), nb2 = __uint_as_float(mb.y); \
    float nc = __uint_as_float(mc.y), nd = __uint_as_float(md.y);  \
    ACC8(pa, na) ACC8(pb, nb2) ACC8(pc, nc) ACC8(pd, nd)           \
  }                                                                \
  for (; e + 4 <= cnt; e += 4) {                                   \
    uint2 m = MP[e + slot];                                        \
    float n = __uint_as_float(m.y);                                \
    uint4 p = *(const uint4*)(x + (size_t)m.x * KK + cg * 8);      \
    ACC8(p, n)                                                     \
  }                                                                \
  if (e + slot < cnt) {                                            \
    uint2 m = MP[e + slot];                                        \
    float n = __uint_as_float(m.y);                                \
    uint4 p = *(const uint4*)(x + (size_t)m.x * KK + cg * 8);      \
    ACC8(p, n)                                                     \
  }

__global__ __launch_bounds__(512) void k_layer(
    const u16* __restrict__ x, const u32* __restrict__ rps,
    const uint2* __restrict__ edatas, const u16* __restrict__ Bsw,
    const float* __restrict__ bsum, u16* __restrict__ hout,
    const float* __restrict__ entity, float* __restrict__ Sx,
    float* __restrict__ Ss, u16* __restrict__ Ssb, int mode)
{
  __shared__ u16 At[RPB][392];            // 12.25 KB; row stride 784B -> 2-way (free)
  __shared__ uint2 meta[3][CAP];          // 12 KB staged edge metadata
  __shared__ u32 rpl[3][RPB + 1];         // row pointers
  const int tid = threadIdx.x;
  const int wv = tid >> 6, lane = tid & 63;
  const int m0 = blockIdx.x * RPB;
  const int slot = lane >> 4, cg = lane & 15;

  if (tid < 3 * (RPB + 1))
    rpl[tid / (RPB + 1)][tid % (RPB + 1)] =
        rps[(size_t)(tid / (RPB + 1)) * (NN + 1) + m0 + tid % (RPB + 1)];
  __syncthreads();

  // ---- stage edge metadata (contiguous CSR slices) ----
  #pragma unroll
  for (int g = 0; g < 3; ++g) {
    u32 b0 = rpl[g][0];
    u32 cnt = rpl[g][RPB] - b0; if (cnt > CAP) cnt = CAP;
    const uint2* ed = edatas + (size_t)g * EE + b0;
    for (u32 i = tid; i < cnt; i += 512) meta[g][i] = ed[i];
  }
  __syncthreads();

  // ---- SpMM phase: 48 tasks ----
  for (int t = wv; t < 48; t += 8) {
    int g = t >> 4, r = t & 15;
    u32 beg = rpl[g][r], end = rpl[g][r + 1];
    u32 cnt = end - beg, e = 0;
    float acc[8] = {0.f, 0.f, 0.f, 0.f, 0.f, 0.f, 0.f, 0.f};
    if (end - rpl[g][0] <= CAP) {
      const uint2* mp = &meta[g][beg - rpl[g][0]];
      GATHER_LOOP(mp)
    } else {                              // overflow fallback (rare)
      const uint2* mp = edatas + (size_t)g * EE + beg;
      GATHER_LOOP(mp)
    }
    #pragma unroll
    for (int i = 0; i < 8; ++i) {
      acc[i] += __shfl_xor(acc[i], 16);
      acc[i] += __shfl_xor(acc[i], 32);
    }
    if (slot == 0) {
      u32 o0 = ((u32)f2bf(acc[1]) << 16) | (u32)f2bf(acc[0]);
      u32 o1 = ((u32)f2bf(acc[3]) << 16) | (u32)f2bf(acc[2]);
      u32 o2 = ((u32)f2bf(acc[5]) << 16) | (u32)f2bf(acc[4]);
      u32 o3 = ((u32)f2bf(acc[7]) << 16) | (u32)f2bf(acc[6]);
      *(uint4*)(&At[r][g * KK + cg * 8]) = make_uint4(o0, o1, o2, o3);
    }
  }
  __syncthreads();

  // ---- MFMA phase: 16x128 = At(16x384) @ B(384x128); wave wv -> cols wv*16.. ----
  const int lr = lane & 15, lk = lane >> 4;
  f32x4 acc2 = {0.f, 0.f, 0.f, 0.f};
  const u16* aB = Bsw + (size_t)wv * 6144 + (size_t)lane * 8;
  #pragma unroll
  for (int ks = 0; ks < 12; ++ks) {
    bf16x8 a = *(const bf16x8*)(&At[lr][ks * 32 + lk * 8]);
    bf16x8 b = *(const bf16x8*)(aB + ks * 512);
    acc2 = __builtin_amdgcn_mfma_f32_16x16x32_bf16(a, b, acc2, 0, 0, 0);
  }

  int col = wv * 16 + lr;
  float bv = bsum[col];
  int rowb = m0 + lk * 4;
  #pragma unroll
  for (int r = 0; r < 4; ++r) {
    size_t idx = (size_t)(rowb + r) * KK + col;
    float v = acc2[r] + bv;
    if (!(mode & 8)) hout[idx] = f2bf(v);
    float sx = (mode & 1) ? (entity[idx] + v) : (Sx[idx] + v);
    Sx[idx] = sx;
    if (mode & 2) Ss[idx] = v;
    else if (mode & 4) Ssb[idx] = f2bf(Ss[idx] + v);
  }
}

// ---------------- fused post: history mean (quad rows) + concept projections ----------

__global__ __launch_bounds__(256) void k_post(
    const u16* __restrict__ Ssb, const int* __restrict__ hist, const int* __restrict__ hlen,
    float* __restrict__ semb, const float* __restrict__ Sx,
    const float* __restrict__ Wstu, const float* __restrict__ Wexer,
    float* __restrict__ cstu, float* __restrict__ cexer)
{
  int wv = threadIdx.x >> 6, lane = threadIdx.x & 63;
  if (blockIdx.x < 512) {                 // stuemb: 2048 items
    int item = blockIdx.x * 4 + wv;
    int slot = lane >> 4, cg = lane & 15;
    int len = hlen[item];
    const int* hrow = hist + item * HH;
    float acc[8] = {0.f, 0.f, 0.f, 0.f, 0.f, 0.f, 0.f, 0.f};
    int h = 0;
    for (; h + 4 <= len; h += 4) {
      int id = hrow[h + slot];
      uint4 p = *(const uint4*)(Ssb + (size_t)(KK + id) * KK + cg * 8);
      acc[0] += bflo(p.x); acc[1] += bfhi(p.x);
      acc[2] += bflo(p.y); acc[3] += bfhi(p.y);
      acc[4] += bflo(p.z); acc[5] += bfhi(p.z);
      acc[6] += bflo(p.w); acc[7] += bfhi(p.w);
    }
    if (h + slot < len) {
      int id = hrow[h + slot];
      uint4 p = *(const uint4*)(Ssb + (size_t)(KK + id) * KK + cg * 8);
      acc[0] += bflo(p.x); acc[1] += bfhi(p.x);
      acc[2] += bflo(p.y); acc[3] += bfhi(p.y);
      acc[4] += bflo(p.z); acc[5] += bfhi(p.z);
      acc[6] += bflo(p.w); acc[7] += bfhi(p.w);
    }
    #pragma unroll
    for (int i = 0; i < 8; ++i) {
      acc[i] += __shfl_xor(acc[i], 16);
      acc[i] += __shfl_xor(acc[i], 32);
    }
    if (slot == 0) {
      float sc = 0.5f / (float)len;
      float4 o0 = make_float4(acc[0] * sc, acc[1] * sc, acc[2] * sc, acc[3] * sc);
      float4 o1 = make_float4(acc[4] * sc, acc[5] * sc, acc[6] * sc, acc[7] * sc);
      *(float4*)(semb + (size_t)item * KK + cg * 8) = o0;
      *(float4*)(semb + (size_t)item * KK + cg * 8 + 4) = o1;
    }
  } else {                                // cproj: 128 concept rows
    int w = (blockIdx.x - 512) * 4 + wv;
    float2 c = *(const float2*)(Sx + (size_t)w * KK + lane * 2);
    c.x *= 0.25f; c.y *= 0.25f;
    float2 ws = *(const float2*)(Wstu + KK + lane * 2);
    float2 we = *(const float2*)(Wexer + KK + lane * 2);
    float ps = c.x * ws.x + c.y * ws.y;
    float pe = c.x * we.x + c.y * we.y;
    #pragma unroll
    for (int off = 32; off; off >>= 1) { ps += __shfl_xor(ps, off); pe += __shfl_xor(pe, off); }
    if (lane == 0) { cstu[w] = ps; cexer[w] = pe; }
  }
}

__global__ void k_final(const float* __restrict__ Sx, const float* __restrict__ semb,
                        const float* __restrict__ cstu, const float* __restrict__ cexer,
                        const float* __restrict__ Wstu, const float* __restrict__ Wexer,
                        const float* __restrict__ W3, const float* __restrict__ disc,
                        const int* __restrict__ exid, const float* __restrict__ kn,
                        const float* __restrict__ bstu, const float* __restrict__ bexer,
                        const float* __restrict__ b3, float* __restrict__ out) {
  int w = (blockIdx.x * 256 + threadIdx.x) >> 6;   // batch index
  int lane = threadIdx.x & 63;
  if (w >= BB) return;
  int eid = exid[w];
  float2 se = *(const float2*)(Sx + ((size_t)(KK + eid)) * KK + lane * 2);
  se.x *= 0.25f; se.y *= 0.25f;                    // exer_emb
  float2 sm = *(const float2*)(semb + (size_t)w * KK + lane * 2);
  float2 ws = *(const float2*)(Wstu + lane * 2);
  float2 we = *(const float2*)(Wexer + lane * 2);
  float ps = sm.x * ws.x + sm.y * ws.y;
  float pe = se.x * we.x + se.y * we.y;
  #pragma unroll
  for (int off = 32; off; off >>= 1) { ps += __shfl_xor(ps, off); pe += __shfl_xor(pe, off); }
  float s_stu = ps + bstu[0];
  float s_exer = pe + bexer[0];
  float ed = 10.f * sgm(disc[eid]);
  float2 cs = *(const float2*)(cstu + lane * 2);
  float2 ce = *(const float2*)(cexer + lane * 2);
  float2 knv = *(const float2*)(kn + (size_t)w * KK + lane * 2);
  float x0 = ed * (sgm(s_stu + cs.x) - sgm(s_exer + ce.x)) * knv.x;
  float x1 = ed * (sgm(s_stu + cs.y) - sgm(s_exer + ce.y)) * knv.y;
  float2 w3v = *(const float2*)(W3 + lane * 2);
  float px = x0 * w3v.x + x1 * w3v.y;
  #pragma unroll
  for (int off = 32; off; off >>= 1) px += __shfl_xor(px, off);
  if (lane == 0) out[w] = sgm(px + b3[0]);
}

// ---------------- host ----------------

extern "C" void kernel_launch(void* const* d_in, const int* in_sizes, int n_in,
                              void* d_out, int out_size, void* d_ws, size_t ws_size,
                              hipStream_t stream)
{
  const float* entity = (const float*)d_in[0];
  const float* gcnW   = (const float*)d_in[1];
  const float* gcnB   = (const float*)d_in[2];
  const float* disc   = (const float*)d_in[3];
  const float* Wstu   = (const float*)d_in[4];
  const float* bstu   = (const float*)d_in[5];
  const float* Wexer  = (const float*)d_in[6];
  const float* bexer  = (const float*)d_in[7];
  const float* W3     = (const float*)d_in[8];
  const float* b3     = (const float*)d_in[9];
  const float* kn     = (const float*)d_in[10];
  const int* exer_id  = (const int*)d_in[12];
  const int* history  = (const int*)d_in[14];
  const int* hlen     = (const int*)d_in[15];
  const int* s0 = (const int*)d_in[16], *dd0 = (const int*)d_in[17];
  const int* s1 = (const int*)d_in[18], *dd1 = (const int*)d_in[19];
  const int* s2 = (const int*)d_in[20], *dd2 = (const int*)d_in[21];

  char* ws = (char*)d_ws;
  size_t off = 0;
  auto take = [&](size_t bytes) -> char* {
    char* p = ws + off;
    off = (off + bytes + 255) & ~(size_t)255;
    return p;
  };
  u16*   xent  = (u16*)take(NKf * 2);
  u16*   hA    = (u16*)take(NKf * 2);
  u16*   hB    = (u16*)take(NKf * 2);
  float* Sx    = (float*)take(NKf * 4);
  float* Ss    = (float*)take(NKf * 4);
  u16*   Ssb   = (u16*)take(NKf * 2);
  float* semb  = (float*)take((size_t)BB * KK * 4);
  float* cstu  = (float*)take(KK * 4);
  float* cexer = (float*)take(KK * 4);
  u16*   Bsw   = (u16*)take((size_t)3 * 49152 * 2);
  float* bsum  = (float*)take((size_t)3 * KK * 4);
  u32*   degI  = (u32*)take((size_t)3 * NN * 4);
  float* rsdO  = (float*)take((size_t)3 * NN * 4);
  float* rsdI  = (float*)take((size_t)3 * NN * 4);
  u32*   rp    = (u32*)take((size_t)3 * (NN + 1) * 4);
  uint2* edata = (uint2*)take((size_t)3 * EE * 8);
  u32*   slabO = (u32*)take((size_t)3 * NB * NP * 4);
  u32*   slabI = (u32*)take((size_t)3 * NB * NP * 4);
  (void)ws_size; (void)in_sizes; (void)n_in; (void)out_size;

  k_hist<<<dim3(NB, 3), 256, 0, stream>>>(s0, dd0, s1, dd1, s2, dd2, slabO, slabI);
  k_reduce<<<dim3((NP + 255) / 256, 3), 256, 0, stream>>>(slabO, slabI, degI, rsdO, rsdI);
  k_exscan2<<<3, 1024, 0, stream>>>(degI, rp);
  k_scatter2<<<dim3(NB, 3), 256, 0, stream>>>(s0, dd0, s1, dd1, s2, dd2, slabI, rp,
                                              rsdO, rsdI, edata);
  k_prep<<<1106, 256, 0, stream>>>(entity, xent, gcnW, Bsw, gcnB, bsum);

  const u16* xs[3] = {xent, hA, hB};
  u16* outs[3]     = {hA, hB, hA};
  const int modes[3] = {1, 2, 4 | 8};
  for (int l = 0; l < 3; ++l)
    k_layer<<<NN / RPB, 512, 0, stream>>>(xs[l], rp, edata, Bsw + (size_t)l * 49152,
                                          bsum + (size_t)l * KK, outs[l], entity,
                                          Sx, Ss, Ssb, modes[l]);

  k_post<<<544, 256, 0, stream>>>(Ssb, history, hlen, semb, Sx, Wstu, Wexer, cstu, cexer);
  k_final<<<BB * 64 / 256, 256, 0, stream>>>(Sx, semb, cstu, cexer, Wstu, Wexer, W3, disc,
                                             exer_id, kn, bstu, bexer, b3, (float*)d_out);
}